// Round 1
// baseline (201.502 us; speedup 1.0000x reference)
//
#include <hip/hip_runtime.h>
#include <cstdint>
#include <cstddef>

// Problem constants
#define BB 8
#define TT 1024
#define CC 512
#define HH 8
#define DD 64
#define MM (BB*TT)     // 8192 rows
#define KCAT 1024      // split-K (hi|lo)
#define NQKV 1536      // q|k|v fused N

typedef short bf16x8 __attribute__((ext_vector_type(8)));
typedef float f32x4  __attribute__((ext_vector_type(4)));

__device__ __forceinline__ short f2bf(float f) {
  unsigned u = __builtin_bit_cast(unsigned, f);
  unsigned r = (u + 0x7FFFu + ((u >> 16) & 1u)) >> 16;
  return (short)r;
}
__device__ __forceinline__ float bf2f(short s) {
  unsigned u = ((unsigned)(unsigned short)s) << 16;
  return __builtin_bit_cast(float, u);
}

__device__ __forceinline__ f32x4 mfma16(bf16x8 a, bf16x8 b, f32x4 c) {
  return __builtin_amdgcn_mfma_f32_16x16x32_bf16(a, b, c, 0, 0, 0);
}

__device__ __forceinline__ void gload_lds16(const void* g, void* l) {
  __builtin_amdgcn_global_load_lds(
      (const __attribute__((address_space(1))) unsigned int*)g,
      (__attribute__((address_space(3))) unsigned int*)l, 16, 0, 0);
}

// ---------------------------------------------------------------------------
// Kernel 1: precision prep.
//   x (8192x512 fp32) -> Xcat (8192x1024 bf16): cols [0,512)=hi, [512,1024)=lo
//   Wq|Wk|Wv (512x512 each) -> Wqkv (1536x1024 bf16), weight duplicated in
//   both K-halves so [xh|xl]@[w|w]^T == x@w^T with exact activations.
//   Wp -> Wpc (512x1024 bf16) likewise.
// ---------------------------------------------------------------------------
__global__ void prep_kernel(const float* __restrict__ x,
                            const float* __restrict__ Wq,
                            const float* __restrict__ Wk,
                            const float* __restrict__ Wv,
                            const float* __restrict__ Wp,
                            short* __restrict__ Xcat,
                            short* __restrict__ Wqkv,
                            short* __restrict__ Wpc) {
  const int NX = MM * CC;          // 4,194,304
  const int NW = CC * CC;          // 262,144
  int stride = gridDim.x * blockDim.x;
  for (int i = blockIdx.x * blockDim.x + threadIdx.x; i < NX + 4 * NW; i += stride) {
    if (i < NX) {
      int m = i >> 9, c = i & 511;
      float v = x[i];
      short hi = f2bf(v);
      short lo = f2bf(v - bf2f(hi));
      Xcat[(size_t)m * KCAT + c] = hi;
      Xcat[(size_t)m * KCAT + 512 + c] = lo;
    } else {
      int wi = i - NX;
      int wsel = wi >> 18;                 // 0=Wq 1=Wk 2=Wv 3=Wp
      int r = (wi >> 9) & 511, c = wi & 511;
      const float* W = (wsel == 0) ? Wq : (wsel == 1) ? Wk : (wsel == 2) ? Wv : Wp;
      short hb = f2bf(W[(size_t)r * CC + c]);
      if (wsel < 3) {
        short* dst = Wqkv + (size_t)(wsel * 512 + r) * KCAT;
        dst[c] = hb; dst[512 + c] = hb;
      } else {
        short* dst = Wpc + (size_t)r * KCAT;
        dst[c] = hb; dst[512 + c] = hb;
      }
    }
  }
}

// ---------------------------------------------------------------------------
// GEMM: A[M][1024] bf16 @ Bw[N][1024]^T, 128x128 tile, BK=64, 4 waves (2x2),
// each wave 64x64 via 4x4 mfma_16x16x32 fragments. global_load_lds staging.
// EPI==0: N=1536, scatter to q,k (B,H,T,64) bf16 and vt (B,H,64,T) bf16 +bias
// EPI==1: N=512, out fp32 = acc + bias
// ---------------------------------------------------------------------------
template <int EPI>
__global__ __launch_bounds__(256, 2) void gemm_kernel(
    const short* __restrict__ A, const short* __restrict__ Bw,
    const float* __restrict__ b0, const float* __restrict__ b1,
    const float* __restrict__ b2,
    short* __restrict__ qo, short* __restrict__ ko, short* __restrict__ vt,
    float* __restrict__ outp) {
  __shared__ short As[128][64];
  __shared__ short Bs[128][64];

  const int tid = threadIdx.x;
  const int lane = tid & 63;
  const int w = tid >> 6;
  const int bm = blockIdx.x, bn = blockIdx.y;
  const int rowA = bm * 128;
  const int rowB = bn * 128;
  const int l15 = lane & 15, lg = lane >> 4;
  const int lr = lane >> 3;          // staging row within 8-row group
  const int lc = (lane & 7) * 8;     // staging col (elements)

  f32x4 acc[4][4] = {};
  const int ar = (w >> 1) * 64;
  const int bc = (w & 1) * 64;

  for (int k0 = 0; k0 < KCAT; k0 += 64) {
#pragma unroll
    for (int i = 0; i < 4; ++i) {
      int r0 = (w * 4 + i) * 8;
      gload_lds16(A + (size_t)(rowA + r0 + lr) * KCAT + k0 + lc, &As[r0][0]);
      gload_lds16(Bw + (size_t)(rowB + r0 + lr) * KCAT + k0 + lc, &Bs[r0][0]);
    }
    __syncthreads();
#pragma unroll
    for (int kk = 0; kk < 2; ++kk) {
      bf16x8 af[4], bf[4];
#pragma unroll
      for (int m = 0; m < 4; ++m)
        af[m] = *(const bf16x8*)&As[ar + m * 16 + l15][kk * 32 + lg * 8];
#pragma unroll
      for (int n = 0; n < 4; ++n)
        bf[n] = *(const bf16x8*)&Bs[bc + n * 16 + l15][kk * 32 + lg * 8];
#pragma unroll
      for (int m = 0; m < 4; ++m)
#pragma unroll
        for (int n = 0; n < 4; ++n)
          acc[m][n] = mfma16(af[m], bf[n], acc[m][n]);
    }
    __syncthreads();
  }

  // epilogue: C row = rowA+ar+m*16+lg*4+j, col = rowB+bc+n*16+l15
#pragma unroll
  for (int m = 0; m < 4; ++m) {
    int rbase = rowA + ar + m * 16 + lg * 4;
#pragma unroll
    for (int n = 0; n < 4; ++n) {
      int col = rowB + bc + n * 16 + l15;
#pragma unroll
      for (int j = 0; j < 4; ++j) {
        float v = acc[m][n][j];
        int r = rbase + j;
        if constexpr (EPI == 0) {
          int b = r >> 10, t = r & 1023;
          int wsel = col >> 9, c = col & 511;
          int h = c >> 6, dd = c & 63;
          int bh = b * HH + h;
          if (wsel == 0) {
            qo[((size_t)bh * TT + t) * DD + dd] = f2bf(v + b0[c]);
          } else if (wsel == 1) {
            ko[((size_t)bh * TT + t) * DD + dd] = f2bf(v + b1[c]);
          } else {
            vt[((size_t)bh * DD + dd) * TT + t] = f2bf(v + b2[c]);
          }
        } else {
          outp[(size_t)r * CC + col] = v + b0[col];
        }
      }
    }
  }
}

// ---------------------------------------------------------------------------
// Flash attention, block-causal over 8-token frames.
// Grid: (B*H) * 16 q-blocks of 64 rows. 4 waves, each owns 16 q-rows.
// q,k: (B,H,T,64) bf16; vt: (B,H,64,T) bf16. Out: Ycat (8192x1024 hi|lo bf16).
// ---------------------------------------------------------------------------
__global__ __launch_bounds__(256, 2) void attn_kernel(
    const short* __restrict__ q, const short* __restrict__ k,
    const short* __restrict__ vt, const float* __restrict__ mask,
    short* __restrict__ Ycat) {
  const int blk = blockIdx.x;
  const int qb = blk & 15;
  const int bh = blk >> 4;
  const int b = bh >> 3, h = bh & 7;
  const int tid = threadIdx.x;
  const int lane = tid & 63;
  const int w = tid >> 6;
  const int l15 = lane & 15, lg = lane >> 4;

  __shared__ short P_lds[4][16][64];

  // Q fragments for this wave's 16 rows (A-operand: row = lane&15)
  const int qrow = qb * 64 + w * 16 + l15;
  const short* qptr = q + ((size_t)bh * TT + qrow) * DD;
  bf16x8 qf[2];
  qf[0] = *(const bf16x8*)(qptr + lg * 8);
  qf[1] = *(const bf16x8*)(qptr + 32 + lg * 8);

  f32x4 yacc[4] = {};
  float mrun[4], lrun[4];
#pragma unroll
  for (int jj = 0; jj < 4; ++jj) { mrun[jj] = -1e30f; lrun[jj] = 0.f; }

  for (int jt = 0; jt <= qb; ++jt) {
    // S = q @ K^T for 64-key tile
    f32x4 sacc[4] = {};
#pragma unroll
    for (int c = 0; c < 2; ++c) {
#pragma unroll
      for (int n = 0; n < 4; ++n) {
        int krow = jt * 64 + n * 16 + l15;
        bf16x8 kf = *(const bf16x8*)(k + ((size_t)bh * TT + krow) * DD + c * 32 + lg * 8);
        sacc[n] = mfma16(qf[c], kf, sacc[n]);
      }
    }
    // scale + masks (input mask everywhere; frame-causal on diagonal tile)
#pragma unroll
    for (int n = 0; n < 4; ++n) {
      int kcol = jt * 64 + n * 16 + l15;
      float mk = mask[(size_t)b * TT + kcol];
      bool dead = (mk == 0.f);
#pragma unroll
      for (int jj = 0; jj < 4; ++jj) {
        float s = sacc[n][jj] * 0.125f;
        if (dead) s = -1e30f;
        if (jt == qb) {
          int rloc = w * 16 + lg * 4 + jj;
          int kloc = n * 16 + l15;
          if ((kloc >> 3) > (rloc >> 3)) s = -1e30f;
        }
        sacc[n][jj] = s;
      }
    }
    // row max across 64 keys (16 lanes of the l>>4 group hold the row)
    float pm[4];
#pragma unroll
    for (int jj = 0; jj < 4; ++jj)
      pm[jj] = fmaxf(fmaxf(sacc[0][jj], sacc[1][jj]), fmaxf(sacc[2][jj], sacc[3][jj]));
#pragma unroll
    for (int d = 1; d < 16; d <<= 1)
#pragma unroll
      for (int jj = 0; jj < 4; ++jj)
        pm[jj] = fmaxf(pm[jj], __shfl_xor(pm[jj], d));
    float alpha[4];
#pragma unroll
    for (int jj = 0; jj < 4; ++jj) {
      float mnew = fmaxf(mrun[jj], pm[jj]);
      alpha[jj] = __expf(mrun[jj] - mnew);
      mrun[jj] = mnew;
    }
    // P = exp(S - m), row sums
    float ps[4] = {0.f, 0.f, 0.f, 0.f};
#pragma unroll
    for (int n = 0; n < 4; ++n)
#pragma unroll
      for (int jj = 0; jj < 4; ++jj) {
        float p = __expf(sacc[n][jj] - mrun[jj]);
        sacc[n][jj] = p;
        ps[jj] += p;
      }
#pragma unroll
    for (int d = 1; d < 16; d <<= 1)
#pragma unroll
      for (int jj = 0; jj < 4; ++jj)
        ps[jj] += __shfl_xor(ps[jj], d);
#pragma unroll
    for (int jj = 0; jj < 4; ++jj) {
      lrun[jj] = lrun[jj] * alpha[jj] + ps[jj];
#pragma unroll
      for (int dt = 0; dt < 4; ++dt) yacc[dt][jj] *= alpha[jj];
    }
    // P -> LDS (C-layout write, A-fragment read) in bf16
#pragma unroll
    for (int n = 0; n < 4; ++n)
#pragma unroll
      for (int jj = 0; jj < 4; ++jj)
        P_lds[w][lg * 4 + jj][n * 16 + l15] = f2bf(sacc[n][jj]);
    // PV: y += P @ V  (V consumed via transposed vt, contiguous in key)
#pragma unroll
    for (int c = 0; c < 2; ++c) {
      bf16x8 pa = *(const bf16x8*)&P_lds[w][l15][c * 32 + lg * 8];
#pragma unroll
      for (int dt = 0; dt < 4; ++dt) {
        bf16x8 vf = *(const bf16x8*)(vt + ((size_t)bh * DD + dt * 16 + l15) * TT + jt * 64 + c * 32 + lg * 8);
        yacc[dt] = mfma16(pa, vf, yacc[dt]);
      }
    }
  }

  // epilogue: y/l, split hi/lo into Ycat
#pragma unroll
  for (int dt = 0; dt < 4; ++dt)
#pragma unroll
    for (int jj = 0; jj < 4; ++jj) {
      float y = yacc[dt][jj] / lrun[jj];
      int row = b * TT + qb * 64 + w * 16 + lg * 4 + jj;
      int col = h * DD + dt * 16 + l15;
      short hi = f2bf(y);
      short lo = f2bf(y - bf2f(hi));
      Ycat[(size_t)row * KCAT + col] = hi;
      Ycat[(size_t)row * KCAT + 512 + col] = lo;
    }
}

// ---------------------------------------------------------------------------
extern "C" void kernel_launch(void* const* d_in, const int* in_sizes, int n_in,
                              void* d_out, int out_size, void* d_ws, size_t ws_size,
                              hipStream_t stream) {
  const float* x    = (const float*)d_in[0];
  const float* mask = (const float*)d_in[1];
  const float* Wq   = (const float*)d_in[2];
  const float* bq   = (const float*)d_in[3];
  const float* Wk   = (const float*)d_in[4];
  const float* bk   = (const float*)d_in[5];
  const float* Wv   = (const float*)d_in[6];
  const float* bv   = (const float*)d_in[7];
  const float* Wp   = (const float*)d_in[8];
  const float* bp   = (const float*)d_in[9];
  float* out = (float*)d_out;

  char* ws = (char*)d_ws;
  short* Xcat = (short*)(ws);                         // 16 MB (reused as Ycat)
  short* Wqkv = (short*)(ws + (size_t)16 * 1048576);  // 3 MB
  short* Wpc  = (short*)(ws + (size_t)19 * 1048576);  // 1 MB
  short* qo   = (short*)(ws + (size_t)20 * 1048576);  // 8 MB
  short* ko   = (short*)(ws + (size_t)28 * 1048576);  // 8 MB
  short* vt   = (short*)(ws + (size_t)36 * 1048576);  // 8 MB -> 44 MB total

  prep_kernel<<<2048, 256, 0, stream>>>(x, Wq, Wk, Wv, Wp, Xcat, Wqkv, Wpc);

  gemm_kernel<0><<<dim3(64, 12), 256, 0, stream>>>(
      Xcat, Wqkv, bq, bk, bv, qo, ko, vt, nullptr);

  attn_kernel<<<dim3(64 * 16), 256, 0, stream>>>(qo, ko, vt, mask, Xcat);

  gemm_kernel<1><<<dim3(64, 4), 256, 0, stream>>>(
      Xcat, Wpc, bp, nullptr, nullptr, nullptr, nullptr, nullptr, out);
}

// Round 2
// 123.963 us; speedup vs baseline: 1.6255x; 1.6255x over previous
//
#include <hip/hip_runtime.h>
#include <cstdint>
#include <cstddef>

// Problem constants
#define BB 8
#define TT 1024
#define CC 512
#define HH 8
#define DD 64
#define MM (BB*TT)     // 8192 rows
#define KCAT 1024      // split-K (hi|lo)

typedef short bf16x8 __attribute__((ext_vector_type(8)));
typedef float f32x4  __attribute__((ext_vector_type(4)));

__device__ __forceinline__ short f2bf(float f) {
  unsigned u = __builtin_bit_cast(unsigned, f);
  unsigned r = (u + 0x7FFFu + ((u >> 16) & 1u)) >> 16;
  return (short)r;
}
__device__ __forceinline__ float bf2f(short s) {
  unsigned u = ((unsigned)(unsigned short)s) << 16;
  return __builtin_bit_cast(float, u);
}

__device__ __forceinline__ f32x4 mfma16(bf16x8 a, bf16x8 b, f32x4 c) {
  return __builtin_amdgcn_mfma_f32_16x16x32_bf16(a, b, c, 0, 0, 0);
}

__device__ __forceinline__ void gload_lds16(const void* g, void* l) {
  __builtin_amdgcn_global_load_lds(
      (const __attribute__((address_space(1))) unsigned int*)g,
      (__attribute__((address_space(3))) unsigned int*)l, 16, 0, 0);
}

// ---------------------------------------------------------------------------
// Kernel 1: precision prep + maskAdd.
// ---------------------------------------------------------------------------
__global__ void prep_kernel(const float* __restrict__ x,
                            const float* __restrict__ mask,
                            const float* __restrict__ Wq,
                            const float* __restrict__ Wk,
                            const float* __restrict__ Wv,
                            const float* __restrict__ Wp,
                            short* __restrict__ Xcat,
                            short* __restrict__ Wqkv,
                            short* __restrict__ Wpc,
                            float* __restrict__ maskAdd) {
  const int NX = MM * CC;          // 4,194,304
  const int NW = CC * CC;          // 262,144
  const int NM = BB * TT;          // 8192
  int stride = gridDim.x * blockDim.x;
  for (int i = blockIdx.x * blockDim.x + threadIdx.x; i < NX + 4 * NW + NM; i += stride) {
    if (i < NX) {
      int m = i >> 9, c = i & 511;
      float v = x[i];
      short hi = f2bf(v);
      short lo = f2bf(v - bf2f(hi));
      Xcat[(size_t)m * KCAT + c] = hi;
      Xcat[(size_t)m * KCAT + 512 + c] = lo;
    } else if (i < NX + 4 * NW) {
      int wi = i - NX;
      int wsel = wi >> 18;                 // 0=Wq 1=Wk 2=Wv 3=Wp
      int r = (wi >> 9) & 511, c = wi & 511;
      const float* W = (wsel == 0) ? Wq : (wsel == 1) ? Wk : (wsel == 2) ? Wv : Wp;
      short hb = f2bf(W[(size_t)r * CC + c]);
      if (wsel < 3) {
        short* dst = Wqkv + (size_t)(wsel * 512 + r) * KCAT;
        dst[c] = hb; dst[512 + c] = hb;
      } else {
        short* dst = Wpc + (size_t)r * KCAT;
        dst[c] = hb; dst[512 + c] = hb;
      }
    } else {
      int mi = i - NX - 4 * NW;
      maskAdd[mi] = (mask[mi] == 0.f) ? -1e30f : 0.f;
    }
  }
}

// ---------------------------------------------------------------------------
// GEMM: A[M][1024] bf16 @ Bw[N][1024]^T, 128x128 tile, BK=64, 4 waves (2x2).
// EPI==0: N=1536, scatter q,k -> (B,H,T,64) bf16, v -> vt (B,H,64,T) bf16 +bias
// EPI==1: N=512, out fp32 = acc + bias
// ---------------------------------------------------------------------------
template <int EPI>
__global__ __launch_bounds__(256, 2) void gemm_kernel(
    const short* __restrict__ A, const short* __restrict__ Bw,
    const float* __restrict__ b0, const float* __restrict__ b1,
    const float* __restrict__ b2,
    short* __restrict__ qo, short* __restrict__ ko, short* __restrict__ vt,
    float* __restrict__ outp) {
  __shared__ short As[128][64];
  __shared__ short Bs[128][64];

  const int tid = threadIdx.x;
  const int lane = tid & 63;
  const int w = tid >> 6;
  const int bm = blockIdx.x, bn = blockIdx.y;
  const int rowA = bm * 128;
  const int rowB = bn * 128;
  const int l15 = lane & 15, lg = lane >> 4;
  const int lr = lane >> 3;          // staging row within 8-row group
  const int lc = (lane & 7) * 8;     // staging col (elements)

  f32x4 acc[4][4] = {};
  const int ar = (w >> 1) * 64;
  const int bc = (w & 1) * 64;

  for (int k0 = 0; k0 < KCAT; k0 += 64) {
#pragma unroll
    for (int i = 0; i < 4; ++i) {
      int r0 = (w * 4 + i) * 8;
      gload_lds16(A + (size_t)(rowA + r0 + lr) * KCAT + k0 + lc, &As[r0][0]);
      gload_lds16(Bw + (size_t)(rowB + r0 + lr) * KCAT + k0 + lc, &Bs[r0][0]);
    }
    __syncthreads();
#pragma unroll
    for (int kk = 0; kk < 2; ++kk) {
      bf16x8 af[4], bf[4];
#pragma unroll
      for (int m = 0; m < 4; ++m)
        af[m] = *(const bf16x8*)&As[ar + m * 16 + l15][kk * 32 + lg * 8];
#pragma unroll
      for (int n = 0; n < 4; ++n)
        bf[n] = *(const bf16x8*)&Bs[bc + n * 16 + l15][kk * 32 + lg * 8];
#pragma unroll
      for (int m = 0; m < 4; ++m)
#pragma unroll
        for (int n = 0; n < 4; ++n)
          acc[m][n] = mfma16(af[m], bf[n], acc[m][n]);
    }
    __syncthreads();
  }

  // epilogue: C row = rowA+ar+m*16+lg*4+j, col = rowB+bc+n*16+l15
#pragma unroll
  for (int m = 0; m < 4; ++m) {
    int rbase = rowA + ar + m * 16 + lg * 4;
#pragma unroll
    for (int n = 0; n < 4; ++n) {
      int col = rowB + bc + n * 16 + l15;
#pragma unroll
      for (int j = 0; j < 4; ++j) {
        float v = acc[m][n][j];
        int r = rbase + j;
        if constexpr (EPI == 0) {
          int b = r >> 10, t = r & 1023;
          int wsel = col >> 9, c = col & 511;
          int h = c >> 6, dd = c & 63;
          int bh = b * HH + h;
          if (wsel == 0) {
            qo[((size_t)bh * TT + t) * DD + dd] = f2bf(v + b0[c]);
          } else if (wsel == 1) {
            ko[((size_t)bh * TT + t) * DD + dd] = f2bf(v + b1[c]);
          } else {
            vt[((size_t)bh * DD + dd) * TT + t] = f2bf(v + b2[c]);
          }
        } else {
          outp[(size_t)r * CC + col] = v + b0[col];
        }
      }
    }
  }
}

// ---------------------------------------------------------------------------
// Flash attention v2, block-causal over 8-token frames.
// Grid: (B*H)*16 q-tiles of 64 rows. 4 waves, each owns 16 q-rows.
// K,V staged in LDS (double-buffered, XOR-swizzled via pre-swizzled global
// source). Swapped QK^T (mfma(K,Q)) so softmax is lane-local per q.
// ---------------------------------------------------------------------------
__global__ __launch_bounds__(256, 2) void attn_kernel(
    const short* __restrict__ q, const short* __restrict__ k,
    const short* __restrict__ vt, const float* __restrict__ maskAdd,
    short* __restrict__ Ycat) {
  const int blk = blockIdx.x;
  const int qb = blk & 15;
  const int bh = blk >> 4;
  const int b = bh >> 3, h = bh & 7;
  const int tid = threadIdx.x;
  const int lane = tid & 63;
  const int w = tid >> 6;
  const int l15 = lane & 15, lg = lane >> 4;
  const int lsw = (l15 & 7) << 4;      // read-side swizzle for rows == l15 mod 8

  __shared__ short Ks[2][64 * 64];
  __shared__ short Vs[2][64 * 64];
  __shared__ short Pl[4][16 * 64];

  const short* kbh = k + (size_t)bh * TT * DD;
  const short* vbh = vt + (size_t)bh * DD * TT;

  // staging lane geometry: lane covers row = 8-group + (lane>>3), 16B col chunk
  const int sr = lane >> 3;            // 0..7
  const int scb = (lane & 7) * 16;     // byte col
  const int ssw = sr << 4;             // (row&7)<<4 swizzle

  // Q fragments (B-operand: col = l15 = q-row, elems d = c*32 + lg*8)
  const int qrow = qb * 64 + w * 16 + l15;
  const short* qptr = q + ((size_t)bh * TT + qrow) * DD;
  bf16x8 qf[2];
  qf[0] = *(const bf16x8*)(qptr + lg * 8);
  qf[1] = *(const bf16x8*)(qptr + 32 + lg * 8);

  f32x4 yacc[4] = {};
  float mrun = -1e30f, lrun = 0.f;

  // prologue stage of tile 0
#pragma unroll
  for (int ph = 0; ph < 2; ++ph) {
    int row = w * 8 + ph * 32 + sr;
    gload_lds16((const char*)kbh + (size_t)row * 128 + (scb ^ ssw),
                (char*)&Ks[0][0] + (w * 8 + ph * 32) * 128);
    gload_lds16((const char*)vbh + (size_t)row * 2048 + (scb ^ ssw),
                (char*)&Vs[0][0] + (w * 8 + ph * 32) * 128);
  }
  __syncthreads();

  int buf = 0;
  for (int jt = 0; jt <= qb; ++jt) {
    // async prefetch of next K/V tile into the other buffer
    if (jt < qb) {
      int nt = jt + 1;
#pragma unroll
      for (int ph = 0; ph < 2; ++ph) {
        int row = w * 8 + ph * 32 + sr;
        gload_lds16((const char*)kbh + (size_t)(nt * 64 + row) * 128 + (scb ^ ssw),
                    (char*)&Ks[buf ^ 1][0] + (w * 8 + ph * 32) * 128);
        gload_lds16((const char*)vbh + (size_t)row * 2048 + nt * 128 + (scb ^ ssw),
                    (char*)&Vs[buf ^ 1][0] + (w * 8 + ph * 32) * 128);
      }
    }
    // mask bias (L2-broadcast 16B loads)
    f32x4 mav[4];
#pragma unroll
    for (int n = 0; n < 4; ++n)
      mav[n] = *(const f32x4*)(maskAdd + (size_t)b * TT + jt * 64 + n * 16 + lg * 4);

    // QK^T swapped: sacc[n][jj] = S[k = n*16+lg*4+jj][q = l15]
    f32x4 sacc[4] = {};
#pragma unroll
    for (int c = 0; c < 2; ++c) {
      bf16x8 qc = qf[c];
#pragma unroll
      for (int n = 0; n < 4; ++n) {
        int krow = n * 16 + l15;
        const bf16x8 kf = *(const bf16x8*)((const char*)&Ks[buf][0] + krow * 128 + ((c * 64 + lg * 16) ^ lsw));
        sacc[n] = mfma16(kf, qc, sacc[n]);
      }
    }
    // scale + input mask + frame-causal on diagonal tile
    const int qloc8 = (w * 16 + l15) >> 3;
#pragma unroll
    for (int n = 0; n < 4; ++n)
#pragma unroll
      for (int jj = 0; jj < 4; ++jj) {
        float s = sacc[n][jj] * 0.125f + mav[n][jj];
        if (jt == qb) {
          int kloc = n * 16 + lg * 4 + jj;
          if ((kloc >> 3) > qloc8) s = -1e30f;
        }
        sacc[n][jj] = s;
      }
    // row max: 16 in-lane + 2 shfl (across lg groups)
    float pm = sacc[0][0];
#pragma unroll
    for (int n = 0; n < 4; ++n)
#pragma unroll
      for (int jj = 0; jj < 4; ++jj) pm = fmaxf(pm, sacc[n][jj]);
    pm = fmaxf(pm, __shfl_xor(pm, 16));
    pm = fmaxf(pm, __shfl_xor(pm, 32));
    float mnew = fmaxf(mrun, pm);
    float alpha = __expf(mrun - mnew);
    mrun = mnew;
    // P = exp(S-m): pack 4 consecutive k per n -> 8B ds_write
    float psum = 0.f;
#pragma unroll
    for (int n = 0; n < 4; ++n) {
      float p0 = __expf(sacc[n][0] - mrun);
      float p1 = __expf(sacc[n][1] - mrun);
      float p2 = __expf(sacc[n][2] - mrun);
      float p3 = __expf(sacc[n][3] - mrun);
      psum += (p0 + p1) + (p2 + p3);
      uint2 pw;
      pw.x = (unsigned)(unsigned short)f2bf(p0) | ((unsigned)(unsigned short)f2bf(p1) << 16);
      pw.y = (unsigned)(unsigned short)f2bf(p2) | ((unsigned)(unsigned short)f2bf(p3) << 16);
      *(uint2*)((char*)&Pl[w][0] + l15 * 128 + ((n * 32 + lg * 8) ^ lsw)) = pw;
    }
    psum += __shfl_xor(psum, 16);
    psum += __shfl_xor(psum, 32);
    lrun = lrun * alpha + psum;
    // broadcast alpha to PV row layout (q = lg*4+jj) and rescale y
    float ab[4];
#pragma unroll
    for (int jj = 0; jj < 4; ++jj) ab[jj] = __shfl(alpha, lg * 4 + jj);
#pragma unroll
    for (int dt = 0; dt < 4; ++dt)
#pragma unroll
      for (int jj = 0; jj < 4; ++jj) yacc[dt][jj] *= ab[jj];
    // PV: y[q][d] += P[q][k] V[k][d]
#pragma unroll
    for (int c = 0; c < 2; ++c) {
      const bf16x8 pa = *(const bf16x8*)((const char*)&Pl[w][0] + l15 * 128 + ((c * 64 + lg * 16) ^ lsw));
#pragma unroll
      for (int dt = 0; dt < 4; ++dt) {
        int vrow = dt * 16 + l15;
        const bf16x8 vf = *(const bf16x8*)((const char*)&Vs[buf][0] + vrow * 128 + ((c * 64 + lg * 16) ^ lsw));
        yacc[dt] = mfma16(pa, vf, yacc[dt]);
      }
    }
    __syncthreads();   // drains prefetch vmcnt + all waves' LDS reads
    buf ^= 1;
  }

  // epilogue: y/l, hi/lo split into Ycat
  float lb[4];
#pragma unroll
  for (int jj = 0; jj < 4; ++jj) lb[jj] = 1.f / __shfl(lrun, lg * 4 + jj);
#pragma unroll
  for (int dt = 0; dt < 4; ++dt) {
    int col = h * DD + dt * 16 + l15;
#pragma unroll
    for (int jj = 0; jj < 4; ++jj) {
      int row = b * TT + qb * 64 + w * 16 + lg * 4 + jj;
      float y = yacc[dt][jj] * lb[jj];
      short hi = f2bf(y);
      short lo = f2bf(y - bf2f(hi));
      Ycat[(size_t)row * KCAT + col] = hi;
      Ycat[(size_t)row * KCAT + 512 + col] = lo;
    }
  }
}

// ---------------------------------------------------------------------------
extern "C" void kernel_launch(void* const* d_in, const int* in_sizes, int n_in,
                              void* d_out, int out_size, void* d_ws, size_t ws_size,
                              hipStream_t stream) {
  const float* x    = (const float*)d_in[0];
  const float* mask = (const float*)d_in[1];
  const float* Wq   = (const float*)d_in[2];
  const float* bq   = (const float*)d_in[3];
  const float* Wk   = (const float*)d_in[4];
  const float* bk   = (const float*)d_in[5];
  const float* Wv   = (const float*)d_in[6];
  const float* bv   = (const float*)d_in[7];
  const float* Wp   = (const float*)d_in[8];
  const float* bp   = (const float*)d_in[9];
  float* out = (float*)d_out;

  char* ws = (char*)d_ws;
  short* Xcat = (short*)(ws);                         // 16 MB (reused as Ycat)
  short* Wqkv = (short*)(ws + (size_t)16 * 1048576);  // 3 MB
  short* Wpc  = (short*)(ws + (size_t)19 * 1048576);  // 1 MB
  short* qo   = (short*)(ws + (size_t)20 * 1048576);  // 8 MB
  short* ko   = (short*)(ws + (size_t)28 * 1048576);  // 8 MB
  short* vt   = (short*)(ws + (size_t)36 * 1048576);  // 8 MB
  float* maskAdd = (float*)(ws + (size_t)44 * 1048576); // 32 KB

  prep_kernel<<<2048, 256, 0, stream>>>(x, mask, Wq, Wk, Wv, Wp, Xcat, Wqkv, Wpc, maskAdd);

  gemm_kernel<0><<<dim3(64, 12), 256, 0, stream>>>(
      Xcat, Wqkv, bq, bk, bv, qo, ko, vt, nullptr);

  attn_kernel<<<dim3(64 * 16), 256, 0, stream>>>(qo, ko, vt, maskAdd, Xcat);

  gemm_kernel<1><<<dim3(64, 4), 256, 0, stream>>>(
      Xcat, Wpc, bp, nullptr, nullptr, nullptr, nullptr, nullptr, out);
}

// Round 3
// 121.735 us; speedup vs baseline: 1.6553x; 1.0183x over previous
//
#include <hip/hip_runtime.h>
#include <cstdint>
#include <cstddef>

// Problem constants
#define BB 8
#define TT 1024
#define CC 512
#define HH 8
#define DD 64
#define MM (BB*TT)     // 8192 rows
#define KCAT 1024      // split-K (hi|lo)

typedef short bf16x8 __attribute__((ext_vector_type(8)));
typedef float f32x4  __attribute__((ext_vector_type(4)));

__device__ __forceinline__ short f2bf(float f) {
  unsigned u = __builtin_bit_cast(unsigned, f);
  unsigned r = (u + 0x7FFFu + ((u >> 16) & 1u)) >> 16;
  return (short)r;
}
__device__ __forceinline__ float bf2f(short s) {
  unsigned u = ((unsigned)(unsigned short)s) << 16;
  return __builtin_bit_cast(float, u);
}

__device__ __forceinline__ f32x4 mfma16(bf16x8 a, bf16x8 b, f32x4 c) {
  return __builtin_amdgcn_mfma_f32_16x16x32_bf16(a, b, c, 0, 0, 0);
}

__device__ __forceinline__ void gload_lds16(const void* g, void* l) {
  __builtin_amdgcn_global_load_lds(
      (const __attribute__((address_space(1))) unsigned int*)g,
      (__attribute__((address_space(3))) unsigned int*)l, 16, 0, 0);
}

// ---------------------------------------------------------------------------
// Kernel 1: precision prep + maskAdd.
// ---------------------------------------------------------------------------
__global__ void prep_kernel(const float* __restrict__ x,
                            const float* __restrict__ mask,
                            const float* __restrict__ Wq,
                            const float* __restrict__ Wk,
                            const float* __restrict__ Wv,
                            const float* __restrict__ Wp,
                            short* __restrict__ Xcat,
                            short* __restrict__ Wqkv,
                            short* __restrict__ Wpc,
                            float* __restrict__ maskAdd) {
  const int NX = MM * CC;          // 4,194,304
  const int NW = CC * CC;          // 262,144
  const int NM = BB * TT;          // 8192
  int stride = gridDim.x * blockDim.x;
  for (int i = blockIdx.x * blockDim.x + threadIdx.x; i < NX + 4 * NW + NM; i += stride) {
    if (i < NX) {
      int m = i >> 9, c = i & 511;
      float v = x[i];
      short hi = f2bf(v);
      short lo = f2bf(v - bf2f(hi));
      Xcat[(size_t)m * KCAT + c] = hi;
      Xcat[(size_t)m * KCAT + 512 + c] = lo;
    } else if (i < NX + 4 * NW) {
      int wi = i - NX;
      int wsel = wi >> 18;                 // 0=Wq 1=Wk 2=Wv 3=Wp
      int r = (wi >> 9) & 511, c = wi & 511;
      const float* W = (wsel == 0) ? Wq : (wsel == 1) ? Wk : (wsel == 2) ? Wv : Wp;
      short hb = f2bf(W[(size_t)r * CC + c]);
      if (wsel < 3) {
        short* dst = Wqkv + (size_t)(wsel * 512 + r) * KCAT;
        dst[c] = hb; dst[512 + c] = hb;
      } else {
        short* dst = Wpc + (size_t)r * KCAT;
        dst[c] = hb; dst[512 + c] = hb;
      }
    } else {
      int mi = i - NX - 4 * NW;
      maskAdd[mi] = (mask[mi] == 0.f) ? -1e30f : 0.f;
    }
  }
}

// ---------------------------------------------------------------------------
// Deep-pipelined GEMM (T2+T3+T4+T5): A[M][1024] bf16 @ Bw[N][1024]^T.
// BM=128, BN=template, BK=64. 8 waves (2M x 4N), per-wave 64 x BN/4.
// Ring-3 LDS K-tile buffers; prefetch t+2 issued after the barrier that
// frees its buffer; counted vmcnt (never 0 in main loop); raw s_barrier;
// XOR swizzle (row&7)<<4 via pre-swizzled global source + swizzled ds_read;
// setprio(1) around the MFMA cluster.
// EPI==0: N=1536, scatter q,k -> (B,H,T,64) bf16, v -> vt (B,H,64,T) +bias
// EPI==1: N=512, out fp32 = acc + bias
// ---------------------------------------------------------------------------
template <int BN, int EPI>
__global__ __launch_bounds__(512, 2) void gemm_kernel(
    const short* __restrict__ A, const short* __restrict__ Bw,
    const float* __restrict__ b0, const float* __restrict__ b1,
    const float* __restrict__ b2,
    short* __restrict__ qo, short* __restrict__ ko, short* __restrict__ vt,
    float* __restrict__ outp) {
  constexpr int TILE_BYTES = 16384 + BN * 128;  // A 128x64x2B + B BNx64x2B
  constexpr int NREP = BN / 64;                 // B fragments per wave
  constexpr int NT = KCAT / 64;                 // 16 K-tiles
  __shared__ __align__(1024) char smem[3 * TILE_BYTES];

  const int tid = threadIdx.x;
  const int lane = tid & 63;
  const int w = tid >> 6;                 // 0..7
  const int wm = w >> 2, wn = w & 3;      // 2M x 4N wave grid
  const int l15 = lane & 15, lg = lane >> 4;
  const int lsw = (l15 & 7) << 4;         // read-side swizzle
  const int sr8 = lane >> 3;              // staging row within 8-group
  const int scbsw = ((lane & 7) * 16) ^ (sr8 << 4);  // pre-swizzled src col

  const int rowA = blockIdx.x * 128;
  const int rowB = blockIdx.y * BN;
  const char* Ab = (const char*)A;
  const char* Bb = (const char*)Bw;

  f32x4 acc[4][NREP] = {};

  auto STAGE = [&](int bufsel, int kt) {
    char* base = smem + bufsel * TILE_BYTES;
    const char* asrc = Ab + (size_t)(rowA + sr8) * 2048 + (size_t)kt * 128 + scbsw;
#pragma unroll
    for (int g = 0; g < 2; ++g) {
      int r0 = w * 16 + g * 8;
      gload_lds16(asrc + (size_t)r0 * 2048, base + r0 * 128);
    }
    const char* bsrc = Bb + (size_t)(rowB + sr8) * 2048 + (size_t)kt * 128 + scbsw;
#pragma unroll
    for (int g = 0; g < NREP; ++g) {
      int r0 = (w * NREP + g) * 8;
      gload_lds16(bsrc + (size_t)r0 * 2048, base + 16384 + r0 * 128);
    }
  };

  // prologue: tiles 0,1 in flight
  STAGE(0, 0);
  STAGE(1, 1);

  int bi = 0;
  for (int t = 0; t < NT; ++t) {
    // wait: own loads of tile t landed (tile t+1 may stay in flight)
    if (t == NT - 1) {
      asm volatile("s_waitcnt vmcnt(0)" ::: "memory");
    } else {
      if constexpr (BN == 256) asm volatile("s_waitcnt vmcnt(6)" ::: "memory");
      else                     asm volatile("s_waitcnt vmcnt(4)" ::: "memory");
    }
    asm volatile("s_barrier" ::: "memory");  // all waves: tile t resident; prior reads done
    if (t + 2 < NT) {
      int bs = (bi == 0) ? 2 : bi - 1;       // (t+2)%3 — buffer freed at end of t-1
      STAGE(bs, t + 2);
    }
    const char* bufA = smem + bi * TILE_BYTES;
    const char* bufB = bufA + 16384;
    bf16x8 af[2][4];
    bf16x8 bfr[2][NREP];
#pragma unroll
    for (int kk = 0; kk < 2; ++kk) {
#pragma unroll
      for (int m = 0; m < 4; ++m)
        af[kk][m] = *(const bf16x8*)(bufA + (wm * 64 + m * 16 + l15) * 128 +
                                     ((kk * 64 + lg * 16) ^ lsw));
#pragma unroll
      for (int n = 0; n < NREP; ++n)
        bfr[kk][n] = *(const bf16x8*)(bufB + (wn * (BN / 4) + n * 16 + l15) * 128 +
                                      ((kk * 64 + lg * 16) ^ lsw));
    }
    __builtin_amdgcn_s_setprio(1);
#pragma unroll
    for (int kk = 0; kk < 2; ++kk)
#pragma unroll
      for (int m = 0; m < 4; ++m)
#pragma unroll
        for (int n = 0; n < NREP; ++n)
          acc[m][n] = mfma16(af[kk][m], bfr[kk][n], acc[m][n]);
    __builtin_amdgcn_s_setprio(0);
    bi = (bi + 1 == 3) ? 0 : bi + 1;
  }

  // epilogue: C row = rowA + wm*64 + m*16 + lg*4 + j, col = rowB + wn*(BN/4) + n*16 + l15
#pragma unroll
  for (int m = 0; m < 4; ++m) {
    int rbase = rowA + wm * 64 + m * 16 + lg * 4;
#pragma unroll
    for (int n = 0; n < NREP; ++n) {
      int col = rowB + wn * (BN / 4) + n * 16 + l15;
#pragma unroll
      for (int j = 0; j < 4; ++j) {
        float v = acc[m][n][j];
        int r = rbase + j;
        if constexpr (EPI == 0) {
          int b = r >> 10, t = r & 1023;
          int wsel = col >> 9, c = col & 511;
          int h = c >> 6, dd = c & 63;
          int bh = b * HH + h;
          if (wsel == 0) {
            qo[((size_t)bh * TT + t) * DD + dd] = f2bf(v + b0[c]);
          } else if (wsel == 1) {
            ko[((size_t)bh * TT + t) * DD + dd] = f2bf(v + b1[c]);
          } else {
            vt[((size_t)bh * DD + dd) * TT + t] = f2bf(v + b2[c]);
          }
        } else {
          outp[(size_t)r * CC + col] = v + b0[col];
        }
      }
    }
  }
}

// ---------------------------------------------------------------------------
// Flash attention v2, block-causal over 8-token frames. (unchanged)
// ---------------------------------------------------------------------------
__global__ __launch_bounds__(256, 2) void attn_kernel(
    const short* __restrict__ q, const short* __restrict__ k,
    const short* __restrict__ vt, const float* __restrict__ maskAdd,
    short* __restrict__ Ycat) {
  const int blk = blockIdx.x;
  const int qb = blk & 15;
  const int bh = blk >> 4;
  const int b = bh >> 3, h = bh & 7;
  const int tid = threadIdx.x;
  const int lane = tid & 63;
  const int w = tid >> 6;
  const int l15 = lane & 15, lg = lane >> 4;
  const int lsw = (l15 & 7) << 4;      // read-side swizzle for rows == l15 mod 8

  __shared__ short Ks[2][64 * 64];
  __shared__ short Vs[2][64 * 64];
  __shared__ short Pl[4][16 * 64];

  const short* kbh = k + (size_t)bh * TT * DD;
  const short* vbh = vt + (size_t)bh * DD * TT;

  const int sr = lane >> 3;            // 0..7
  const int scb = (lane & 7) * 16;     // byte col
  const int ssw = sr << 4;             // (row&7)<<4 swizzle

  const int qrow = qb * 64 + w * 16 + l15;
  const short* qptr = q + ((size_t)bh * TT + qrow) * DD;
  bf16x8 qf[2];
  qf[0] = *(const bf16x8*)(qptr + lg * 8);
  qf[1] = *(const bf16x8*)(qptr + 32 + lg * 8);

  f32x4 yacc[4] = {};
  float mrun = -1e30f, lrun = 0.f;

#pragma unroll
  for (int ph = 0; ph < 2; ++ph) {
    int row = w * 8 + ph * 32 + sr;
    gload_lds16((const char*)kbh + (size_t)row * 128 + (scb ^ ssw),
                (char*)&Ks[0][0] + (w * 8 + ph * 32) * 128);
    gload_lds16((const char*)vbh + (size_t)row * 2048 + (scb ^ ssw),
                (char*)&Vs[0][0] + (w * 8 + ph * 32) * 128);
  }
  __syncthreads();

  int buf = 0;
  for (int jt = 0; jt <= qb; ++jt) {
    if (jt < qb) {
      int nt = jt + 1;
#pragma unroll
      for (int ph = 0; ph < 2; ++ph) {
        int row = w * 8 + ph * 32 + sr;
        gload_lds16((const char*)kbh + (size_t)(nt * 64 + row) * 128 + (scb ^ ssw),
                    (char*)&Ks[buf ^ 1][0] + (w * 8 + ph * 32) * 128);
        gload_lds16((const char*)vbh + (size_t)row * 2048 + nt * 128 + (scb ^ ssw),
                    (char*)&Vs[buf ^ 1][0] + (w * 8 + ph * 32) * 128);
      }
    }
    f32x4 mav[4];
#pragma unroll
    for (int n = 0; n < 4; ++n)
      mav[n] = *(const f32x4*)(maskAdd + (size_t)b * TT + jt * 64 + n * 16 + lg * 4);

    f32x4 sacc[4] = {};
#pragma unroll
    for (int c = 0; c < 2; ++c) {
      bf16x8 qc = qf[c];
#pragma unroll
      for (int n = 0; n < 4; ++n) {
        int krow = n * 16 + l15;
        const bf16x8 kf = *(const bf16x8*)((const char*)&Ks[buf][0] + krow * 128 + ((c * 64 + lg * 16) ^ lsw));
        sacc[n] = mfma16(kf, qc, sacc[n]);
      }
    }
    const int qloc8 = (w * 16 + l15) >> 3;
#pragma unroll
    for (int n = 0; n < 4; ++n)
#pragma unroll
      for (int jj = 0; jj < 4; ++jj) {
        float s = sacc[n][jj] * 0.125f + mav[n][jj];
        if (jt == qb) {
          int kloc = n * 16 + lg * 4 + jj;
          if ((kloc >> 3) > qloc8) s = -1e30f;
        }
        sacc[n][jj] = s;
      }
    float pm = sacc[0][0];
#pragma unroll
    for (int n = 0; n < 4; ++n)
#pragma unroll
      for (int jj = 0; jj < 4; ++jj) pm = fmaxf(pm, sacc[n][jj]);
    pm = fmaxf(pm, __shfl_xor(pm, 16));
    pm = fmaxf(pm, __shfl_xor(pm, 32));
    float mnew = fmaxf(mrun, pm);
    float alpha = __expf(mrun - mnew);
    mrun = mnew;
    float psum = 0.f;
#pragma unroll
    for (int n = 0; n < 4; ++n) {
      float p0 = __expf(sacc[n][0] - mrun);
      float p1 = __expf(sacc[n][1] - mrun);
      float p2 = __expf(sacc[n][2] - mrun);
      float p3 = __expf(sacc[n][3] - mrun);
      psum += (p0 + p1) + (p2 + p3);
      uint2 pw;
      pw.x = (unsigned)(unsigned short)f2bf(p0) | ((unsigned)(unsigned short)f2bf(p1) << 16);
      pw.y = (unsigned)(unsigned short)f2bf(p2) | ((unsigned)(unsigned short)f2bf(p3) << 16);
      *(uint2*)((char*)&Pl[w][0] + l15 * 128 + ((n * 32 + lg * 8) ^ lsw)) = pw;
    }
    psum += __shfl_xor(psum, 16);
    psum += __shfl_xor(psum, 32);
    lrun = lrun * alpha + psum;
    float ab[4];
#pragma unroll
    for (int jj = 0; jj < 4; ++jj) ab[jj] = __shfl(alpha, lg * 4 + jj);
#pragma unroll
    for (int dt = 0; dt < 4; ++dt)
#pragma unroll
      for (int jj = 0; jj < 4; ++jj) yacc[dt][jj] *= ab[jj];
#pragma unroll
    for (int c = 0; c < 2; ++c) {
      const bf16x8 pa = *(const bf16x8*)((const char*)&Pl[w][0] + l15 * 128 + ((c * 64 + lg * 16) ^ lsw));
#pragma unroll
      for (int dt = 0; dt < 4; ++dt) {
        int vrow = dt * 16 + l15;
        const bf16x8 vf = *(const bf16x8*)((const char*)&Vs[buf][0] + vrow * 128 + ((c * 64 + lg * 16) ^ lsw));
        yacc[dt] = mfma16(pa, vf, yacc[dt]);
      }
    }
    __syncthreads();
    buf ^= 1;
  }

  float lb[4];
#pragma unroll
  for (int jj = 0; jj < 4; ++jj) lb[jj] = 1.f / __shfl(lrun, lg * 4 + jj);
#pragma unroll
  for (int dt = 0; dt < 4; ++dt) {
    int col = h * DD + dt * 16 + l15;
#pragma unroll
    for (int jj = 0; jj < 4; ++jj) {
      int row = b * TT + qb * 64 + w * 16 + lg * 4 + jj;
      float y = yacc[dt][jj] * lb[jj];
      short hi = f2bf(y);
      short lo = f2bf(y - bf2f(hi));
      Ycat[(size_t)row * KCAT + col] = hi;
      Ycat[(size_t)row * KCAT + 512 + col] = lo;
    }
  }
}

// ---------------------------------------------------------------------------
extern "C" void kernel_launch(void* const* d_in, const int* in_sizes, int n_in,
                              void* d_out, int out_size, void* d_ws, size_t ws_size,
                              hipStream_t stream) {
  const float* x    = (const float*)d_in[0];
  const float* mask = (const float*)d_in[1];
  const float* Wq   = (const float*)d_in[2];
  const float* bq   = (const float*)d_in[3];
  const float* Wk   = (const float*)d_in[4];
  const float* bk   = (const float*)d_in[5];
  const float* Wv   = (const float*)d_in[6];
  const float* bv   = (const float*)d_in[7];
  const float* Wp   = (const float*)d_in[8];
  const float* bp   = (const float*)d_in[9];
  float* out = (float*)d_out;

  char* ws = (char*)d_ws;
  short* Xcat = (short*)(ws);                         // 16 MB (reused as Ycat)
  short* Wqkv = (short*)(ws + (size_t)16 * 1048576);  // 3 MB
  short* Wpc  = (short*)(ws + (size_t)19 * 1048576);  // 1 MB
  short* qo   = (short*)(ws + (size_t)20 * 1048576);  // 8 MB
  short* ko   = (short*)(ws + (size_t)28 * 1048576);  // 8 MB
  short* vt   = (short*)(ws + (size_t)36 * 1048576);  // 8 MB
  float* maskAdd = (float*)(ws + (size_t)44 * 1048576); // 32 KB

  prep_kernel<<<2048, 256, 0, stream>>>(x, mask, Wq, Wk, Wv, Wp, Xcat, Wqkv, Wpc, maskAdd);

  gemm_kernel<256, 0><<<dim3(64, 6), 512, 0, stream>>>(
      Xcat, Wqkv, bq, bk, bv, qo, ko, vt, nullptr);

  attn_kernel<<<dim3(64 * 16), 256, 0, stream>>>(qo, ko, vt, maskAdd, Xcat);

  gemm_kernel<128, 1><<<dim3(64, 4), 512, 0, stream>>>(
      Xcat, Wpc, bp, nullptr, nullptr, nullptr, nullptr, nullptr, out);
}

// Round 4
// 119.857 us; speedup vs baseline: 1.6812x; 1.0157x over previous
//
#include <hip/hip_runtime.h>
#include <cstdint>
#include <cstddef>

// Problem constants
#define BB 8
#define TT 1024
#define CC 512
#define HH 8
#define DD 64
#define MM (BB*TT)     // 8192 rows
#define KCAT 1024      // split-K (hi|lo)

typedef short bf16x8 __attribute__((ext_vector_type(8)));
typedef float f32x4  __attribute__((ext_vector_type(4)));

__device__ __forceinline__ short f2bf(float f) {
  unsigned u = __builtin_bit_cast(unsigned, f);
  unsigned r = (u + 0x7FFFu + ((u >> 16) & 1u)) >> 16;
  return (short)r;
}
__device__ __forceinline__ float bf2f(short s) {
  unsigned u = ((unsigned)(unsigned short)s) << 16;
  return __builtin_bit_cast(float, u);
}

__device__ __forceinline__ f32x4 mfma16(bf16x8 a, bf16x8 b, f32x4 c) {
  return __builtin_amdgcn_mfma_f32_16x16x32_bf16(a, b, c, 0, 0, 0);
}

__device__ __forceinline__ void gload_lds16(const void* g, void* l) {
  __builtin_amdgcn_global_load_lds(
      (const __attribute__((address_space(1))) unsigned int*)g,
      (__attribute__((address_space(3))) unsigned int*)l, 16, 0, 0);
}

// ---------------------------------------------------------------------------
// Kernel 1: precision prep + maskAdd.
// ---------------------------------------------------------------------------
__global__ void prep_kernel(const float* __restrict__ x,
                            const float* __restrict__ mask,
                            const float* __restrict__ Wq,
                            const float* __restrict__ Wk,
                            const float* __restrict__ Wv,
                            const float* __restrict__ Wp,
                            short* __restrict__ Xcat,
                            short* __restrict__ Wqkv,
                            short* __restrict__ Wpc,
                            float* __restrict__ maskAdd) {
  const int NX = MM * CC;          // 4,194,304
  const int NW = CC * CC;          // 262,144
  const int NM = BB * TT;          // 8192
  int stride = gridDim.x * blockDim.x;
  for (int i = blockIdx.x * blockDim.x + threadIdx.x; i < NX + 4 * NW + NM; i += stride) {
    if (i < NX) {
      int m = i >> 9, c = i & 511;
      float v = x[i];
      short hi = f2bf(v);
      short lo = f2bf(v - bf2f(hi));
      Xcat[(size_t)m * KCAT + c] = hi;
      Xcat[(size_t)m * KCAT + 512 + c] = lo;
    } else if (i < NX + 4 * NW) {
      int wi = i - NX;
      int wsel = wi >> 18;                 // 0=Wq 1=Wk 2=Wv 3=Wp
      int r = (wi >> 9) & 511, c = wi & 511;
      const float* W = (wsel == 0) ? Wq : (wsel == 1) ? Wk : (wsel == 2) ? Wv : Wp;
      short hb = f2bf(W[(size_t)r * CC + c]);
      if (wsel < 3) {
        short* dst = Wqkv + (size_t)(wsel * 512 + r) * KCAT;
        dst[c] = hb; dst[512 + c] = hb;
      } else {
        short* dst = Wpc + (size_t)r * KCAT;
        dst[c] = hb; dst[512 + c] = hb;
      }
    } else {
      int mi = i - NX - 4 * NW;
      maskAdd[mi] = (mask[mi] == 0.f) ? -1e30f : 0.f;
    }
  }
}

// ---------------------------------------------------------------------------
// 4-phase-per-K-tile pipelined GEMM (T2+T3+T4+T5), m201-style schedule.
// A[M][1024] bf16 @ Bw[N][1024]^T. BK=64, 8 waves (WM x WN), double-buffered
// LDS. Per K-tile: 4 phases, each {ds_read frag-half || issue stage part ->
// barrier -> lgkmcnt(0) -> setprio(1) -> MFMA quadrant -> setprio(0) ->
// barrier}; one vmcnt(0) per tile at the end (loads span ~6 barriers).
// XOR swizzle (row&7)<<4 via pre-swizzled global source + swizzled ds_read.
// EPI==0: scatter q,k -> (B,H,T,64) bf16, v -> vt (B,H,64,T) +bias
// EPI==1: out fp32 = acc + bias
// ---------------------------------------------------------------------------
template <int BM, int BN, int WM, int WN, int EPI>
__global__ __launch_bounds__(512, 2) void gemm_kernel(
    const short* __restrict__ A, const short* __restrict__ Bw,
    const float* __restrict__ b0, const float* __restrict__ b1,
    const float* __restrict__ b2,
    short* __restrict__ qo, short* __restrict__ ko, short* __restrict__ vt,
    float* __restrict__ outp) {
  constexpr int MR = BM / WM / 16;     // 4
  constexpr int NR = BN / WN / 16;     // 6 (qkv) / 2 (proj)
  constexpr int NH = NR / 2;           // 3 / 1
  constexpr int ABYT = BM * 128;       // A tile bytes
  constexpr int TILE = ABYT + BN * 128;
  constexpr int NT = KCAT / 64;        // 16 K-tiles
  constexpr int AL = BM / 64;          // A gloads per thread per tile
  constexpr int BL = BN / 64;
  __shared__ __align__(1024) char smem[2 * TILE];

  const int tid = threadIdx.x;
  const int lane = tid & 63;
  const int w = tid >> 6;              // 0..7
  const int wm = w / WN, wn = w % WN;
  const int l15 = lane & 15, lg = lane >> 4;
  const int lsw = (l15 & 7) << 4;      // read-side swizzle
  const int sr8 = lane >> 3;
  const int scbsw = ((lane & 7) * 16) ^ (sr8 << 4);  // pre-swizzled src col

  const int rowA = blockIdx.x * BM;
  const int rowB = blockIdx.y * BN;
  const char* Ab = (const char*)A + (size_t)(rowA + sr8) * 2048 + scbsw;
  const char* Bb = (const char*)Bw + (size_t)(rowB + sr8) * 2048 + scbsw;

  f32x4 acc[MR][NR] = {};

  auto STAGE_A = [&](char* dst, int kt) {
#pragma unroll
    for (int g = 0; g < AL; ++g) {
      int r0 = (w * AL + g) * 8;
      gload_lds16(Ab + (size_t)r0 * 2048 + (size_t)kt * 128, dst + r0 * 128);
    }
  };
  auto STAGE_B = [&](char* dst, int kt) {
#pragma unroll
    for (int g = 0; g < BL; ++g) {
      int r0 = (w * BL + g) * 8;
      gload_lds16(Bb + (size_t)r0 * 2048 + (size_t)kt * 128, dst + ABYT + r0 * 128);
    }
  };
  auto RDA = [&](const char* buf, int mh, bf16x8 af[2][2]) {
#pragma unroll
    for (int kk = 0; kk < 2; ++kk)
#pragma unroll
      for (int i = 0; i < 2; ++i) {
        int row = wm * 64 + (mh * 2 + i) * 16 + l15;
        af[kk][i] = *(const bf16x8*)(buf + row * 128 + ((kk * 64 + lg * 16) ^ lsw));
      }
  };
  auto RDB = [&](const char* buf, int nh, bf16x8 bfr[2][NH]) {
#pragma unroll
    for (int kk = 0; kk < 2; ++kk)
#pragma unroll
      for (int j = 0; j < NH; ++j) {
        int row = wn * (BN / WN) + (nh * NH + j) * 16 + l15;
        bfr[kk][j] = *(const bf16x8*)(buf + ABYT + row * 128 + ((kk * 64 + lg * 16) ^ lsw));
      }
  };

  // prologue: stage tile 0, drain once
  STAGE_A(smem, 0);
  STAGE_B(smem, 0);
  asm volatile("s_waitcnt vmcnt(0)" ::: "memory");
  __builtin_amdgcn_s_barrier();

  for (int t = 0; t < NT; ++t) {
    char* bufp = smem + (t & 1) * TILE;
    char* bufn = smem + ((t + 1) & 1) * TILE;
    bf16x8 af[2][2], bfr[2][NH];

#define QUAD(MH, NHI)                                                         \
  __builtin_amdgcn_s_barrier();                                               \
  asm volatile("s_waitcnt lgkmcnt(0)" ::: "memory");                          \
  __builtin_amdgcn_sched_barrier(0);                                          \
  __builtin_amdgcn_s_setprio(1);                                              \
  _Pragma("unroll")                                                           \
  for (int kk = 0; kk < 2; ++kk)                                              \
    _Pragma("unroll")                                                         \
    for (int i = 0; i < 2; ++i)                                               \
      _Pragma("unroll")                                                       \
      for (int j = 0; j < NH; ++j)                                            \
        acc[(MH)*2 + i][(NHI)*NH + j] =                                       \
            mfma16(af[kk][i], bfr[kk][j], acc[(MH)*2 + i][(NHI)*NH + j]);     \
  __builtin_amdgcn_s_setprio(0);

    // phase 0: quadrant (0,0); issue A-stage of t+1
    RDA(bufp, 0, af);
    RDB(bufp, 0, bfr);
    if (t + 1 < NT) STAGE_A(bufn, t + 1);
    QUAD(0, 0)
    __builtin_amdgcn_s_barrier();
    // phase 1: quadrant (0,1); issue B-stage of t+1
    RDB(bufp, 1, bfr);
    if (t + 1 < NT) STAGE_B(bufn, t + 1);
    QUAD(0, 1)
    __builtin_amdgcn_s_barrier();
    // phase 2: quadrant (1,1)
    RDA(bufp, 1, af);
    QUAD(1, 1)
    __builtin_amdgcn_s_barrier();
    // phase 3: quadrant (1,0); re-read B half 0
    RDB(bufp, 0, bfr);
    QUAD(1, 0)
    // tile end: drain own t+1 stage loads (issued ~3 phases ago), then barrier
    asm volatile("s_waitcnt vmcnt(0)" ::: "memory");
    __builtin_amdgcn_s_barrier();
#undef QUAD
  }

  // epilogue: C row = rowA + wm*64 + m*16 + lg*4 + j, col = rowB + wn*(BN/WN) + n*16 + l15
#pragma unroll
  for (int m = 0; m < MR; ++m) {
    int rbase = rowA + wm * 64 + m * 16 + lg * 4;
#pragma unroll
    for (int n = 0; n < NR; ++n) {
      int col = rowB + wn * (BN / WN) + n * 16 + l15;
#pragma unroll
      for (int j = 0; j < 4; ++j) {
        float v = acc[m][n][j];
        int r = rbase + j;
        if constexpr (EPI == 0) {
          int b = r >> 10, t = r & 1023;
          int wsel = col >> 9, c = col & 511;
          int h = c >> 6, dd = c & 63;
          int bh = b * HH + h;
          if (wsel == 0) {
            qo[((size_t)bh * TT + t) * DD + dd] = f2bf(v + b0[c]);
          } else if (wsel == 1) {
            ko[((size_t)bh * TT + t) * DD + dd] = f2bf(v + b1[c]);
          } else {
            vt[((size_t)bh * DD + dd) * TT + t] = f2bf(v + b2[c]);
          }
        } else {
          outp[(size_t)r * CC + col] = v + b0[col];
        }
      }
    }
  }
}

// ---------------------------------------------------------------------------
// Flash attention v2, block-causal over 8-token frames. (unchanged)
// ---------------------------------------------------------------------------
__global__ __launch_bounds__(256, 2) void attn_kernel(
    const short* __restrict__ q, const short* __restrict__ k,
    const short* __restrict__ vt, const float* __restrict__ maskAdd,
    short* __restrict__ Ycat) {
  const int blk = blockIdx.x;
  const int qb = blk & 15;
  const int bh = blk >> 4;
  const int b = bh >> 3, h = bh & 7;
  const int tid = threadIdx.x;
  const int lane = tid & 63;
  const int w = tid >> 6;
  const int l15 = lane & 15, lg = lane >> 4;
  const int lsw = (l15 & 7) << 4;      // read-side swizzle for rows == l15 mod 8

  __shared__ short Ks[2][64 * 64];
  __shared__ short Vs[2][64 * 64];
  __shared__ short Pl[4][16 * 64];

  const short* kbh = k + (size_t)bh * TT * DD;
  const short* vbh = vt + (size_t)bh * DD * TT;

  const int sr = lane >> 3;            // 0..7
  const int scb = (lane & 7) * 16;     // byte col
  const int ssw = sr << 4;             // (row&7)<<4 swizzle

  const int qrow = qb * 64 + w * 16 + l15;
  const short* qptr = q + ((size_t)bh * TT + qrow) * DD;
  bf16x8 qf[2];
  qf[0] = *(const bf16x8*)(qptr + lg * 8);
  qf[1] = *(const bf16x8*)(qptr + 32 + lg * 8);

  f32x4 yacc[4] = {};
  float mrun = -1e30f, lrun = 0.f;

#pragma unroll
  for (int ph = 0; ph < 2; ++ph) {
    int row = w * 8 + ph * 32 + sr;
    gload_lds16((const char*)kbh + (size_t)row * 128 + (scb ^ ssw),
                (char*)&Ks[0][0] + (w * 8 + ph * 32) * 128);
    gload_lds16((const char*)vbh + (size_t)row * 2048 + (scb ^ ssw),
                (char*)&Vs[0][0] + (w * 8 + ph * 32) * 128);
  }
  __syncthreads();

  int buf = 0;
  for (int jt = 0; jt <= qb; ++jt) {
    if (jt < qb) {
      int nt = jt + 1;
#pragma unroll
      for (int ph = 0; ph < 2; ++ph) {
        int row = w * 8 + ph * 32 + sr;
        gload_lds16((const char*)kbh + (size_t)(nt * 64 + row) * 128 + (scb ^ ssw),
                    (char*)&Ks[buf ^ 1][0] + (w * 8 + ph * 32) * 128);
        gload_lds16((const char*)vbh + (size_t)row * 2048 + nt * 128 + (scb ^ ssw),
                    (char*)&Vs[buf ^ 1][0] + (w * 8 + ph * 32) * 128);
      }
    }
    f32x4 mav[4];
#pragma unroll
    for (int n = 0; n < 4; ++n)
      mav[n] = *(const f32x4*)(maskAdd + (size_t)b * TT + jt * 64 + n * 16 + lg * 4);

    f32x4 sacc[4] = {};
#pragma unroll
    for (int c = 0; c < 2; ++c) {
      bf16x8 qc = qf[c];
#pragma unroll
      for (int n = 0; n < 4; ++n) {
        int krow = n * 16 + l15;
        const bf16x8 kf = *(const bf16x8*)((const char*)&Ks[buf][0] + krow * 128 + ((c * 64 + lg * 16) ^ lsw));
        sacc[n] = mfma16(kf, qc, sacc[n]);
      }
    }
    const int qloc8 = (w * 16 + l15) >> 3;
#pragma unroll
    for (int n = 0; n < 4; ++n)
#pragma unroll
      for (int jj = 0; jj < 4; ++jj) {
        float s = sacc[n][jj] * 0.125f + mav[n][jj];
        if (jt == qb) {
          int kloc = n * 16 + lg * 4 + jj;
          if ((kloc >> 3) > qloc8) s = -1e30f;
        }
        sacc[n][jj] = s;
      }
    float pm = sacc[0][0];
#pragma unroll
    for (int n = 0; n < 4; ++n)
#pragma unroll
      for (int jj = 0; jj < 4; ++jj) pm = fmaxf(pm, sacc[n][jj]);
    pm = fmaxf(pm, __shfl_xor(pm, 16));
    pm = fmaxf(pm, __shfl_xor(pm, 32));
    float mnew = fmaxf(mrun, pm);
    float alpha = __expf(mrun - mnew);
    mrun = mnew;
    float psum = 0.f;
#pragma unroll
    for (int n = 0; n < 4; ++n) {
      float p0 = __expf(sacc[n][0] - mrun);
      float p1 = __expf(sacc[n][1] - mrun);
      float p2 = __expf(sacc[n][2] - mrun);
      float p3 = __expf(sacc[n][3] - mrun);
      psum += (p0 + p1) + (p2 + p3);
      uint2 pw;
      pw.x = (unsigned)(unsigned short)f2bf(p0) | ((unsigned)(unsigned short)f2bf(p1) << 16);
      pw.y = (unsigned)(unsigned short)f2bf(p2) | ((unsigned)(unsigned short)f2bf(p3) << 16);
      *(uint2*)((char*)&Pl[w][0] + l15 * 128 + ((n * 32 + lg * 8) ^ lsw)) = pw;
    }
    psum += __shfl_xor(psum, 16);
    psum += __shfl_xor(psum, 32);
    lrun = lrun * alpha + psum;
    float ab[4];
#pragma unroll
    for (int jj = 0; jj < 4; ++jj) ab[jj] = __shfl(alpha, lg * 4 + jj);
#pragma unroll
    for (int dt = 0; dt < 4; ++dt)
#pragma unroll
      for (int jj = 0; jj < 4; ++jj) yacc[dt][jj] *= ab[jj];
#pragma unroll
    for (int c = 0; c < 2; ++c) {
      const bf16x8 pa = *(const bf16x8*)((const char*)&Pl[w][0] + l15 * 128 + ((c * 64 + lg * 16) ^ lsw));
#pragma unroll
      for (int dt = 0; dt < 4; ++dt) {
        int vrow = dt * 16 + l15;
        const bf16x8 vf = *(const bf16x8*)((const char*)&Vs[buf][0] + vrow * 128 + ((c * 64 + lg * 16) ^ lsw));
        yacc[dt] = mfma16(pa, vf, yacc[dt]);
      }
    }
    __syncthreads();
    buf ^= 1;
  }

  float lb[4];
#pragma unroll
  for (int jj = 0; jj < 4; ++jj) lb[jj] = 1.f / __shfl(lrun, lg * 4 + jj);
#pragma unroll
  for (int dt = 0; dt < 4; ++dt) {
    int col = h * DD + dt * 16 + l15;
#pragma unroll
    for (int jj = 0; jj < 4; ++jj) {
      int row = b * TT + qb * 64 + w * 16 + lg * 4 + jj;
      float y = yacc[dt][jj] * lb[jj];
      short hi = f2bf(y);
      short lo = f2bf(y - bf2f(hi));
      Ycat[(size_t)row * KCAT + col] = hi;
      Ycat[(size_t)row * KCAT + 512 + col] = lo;
    }
  }
}

// ---------------------------------------------------------------------------
extern "C" void kernel_launch(void* const* d_in, const int* in_sizes, int n_in,
                              void* d_out, int out_size, void* d_ws, size_t ws_size,
                              hipStream_t stream) {
  const float* x    = (const float*)d_in[0];
  const float* mask = (const float*)d_in[1];
  const float* Wq   = (const float*)d_in[2];
  const float* bq   = (const float*)d_in[3];
  const float* Wk   = (const float*)d_in[4];
  const float* bk   = (const float*)d_in[5];
  const float* Wv   = (const float*)d_in[6];
  const float* bv   = (const float*)d_in[7];
  const float* Wp   = (const float*)d_in[8];
  const float* bp   = (const float*)d_in[9];
  float* out = (float*)d_out;

  char* ws = (char*)d_ws;
  short* Xcat = (short*)(ws);                         // 16 MB (reused as Ycat)
  short* Wqkv = (short*)(ws + (size_t)16 * 1048576);  // 3 MB
  short* Wpc  = (short*)(ws + (size_t)19 * 1048576);  // 1 MB
  short* qo   = (short*)(ws + (size_t)20 * 1048576);  // 8 MB
  short* ko   = (short*)(ws + (size_t)28 * 1048576);  // 8 MB
  short* vt   = (short*)(ws + (size_t)36 * 1048576);  // 8 MB
  float* maskAdd = (float*)(ws + (size_t)44 * 1048576); // 32 KB

  prep_kernel<<<2048, 256, 0, stream>>>(x, mask, Wq, Wk, Wv, Wp, Xcat, Wqkv, Wpc, maskAdd);

  // QKV: M=8192/256=32, N=1536/192=8 -> 256 blocks = 1/CU, one round
  gemm_kernel<256, 192, 4, 2, 0><<<dim3(32, 8), 512, 0, stream>>>(
      Xcat, Wqkv, bq, bk, bv, qo, ko, vt, nullptr);

  attn_kernel<<<dim3(64 * 16), 256, 0, stream>>>(qo, ko, vt, maskAdd, Xcat);

  // proj: M=8192/128=64, N=512/128=4 -> 256 blocks = 1/CU, one round
  gemm_kernel<128, 128, 2, 4, 1><<<dim3(64, 4), 512, 0, stream>>>(
      Xcat, Wpc, bp, nullptr, nullptr, nullptr, nullptr, nullptr, out);
}

// Round 5
// 88.911 us; speedup vs baseline: 2.2663x; 1.3481x over previous
//
#include <hip/hip_runtime.h>
#include <cstdint>
#include <cstddef>

// Problem constants
#define BB 8
#define TT 1024
#define CC 512
#define HH 8
#define DD 64
#define MM (BB*TT)     // 8192 rows

typedef short s16x4 __attribute__((ext_vector_type(4)));
typedef _Float16 f16x8 __attribute__((ext_vector_type(8)));
typedef float f32x4  __attribute__((ext_vector_type(4)));

__device__ __forceinline__ short f2hs(float f) {
  _Float16 h = (_Float16)f;
  return __builtin_bit_cast(short, h);
}

__device__ __forceinline__ f32x4 mfma16h(f16x8 a, f16x8 b, f32x4 c) {
  return __builtin_amdgcn_mfma_f32_16x16x32_f16(a, b, c, 0, 0, 0);
}

__device__ __forceinline__ void gload_lds16(const void* g, void* l) {
  __builtin_amdgcn_global_load_lds(
      (const __attribute__((address_space(1))) unsigned int*)g,
      (__attribute__((address_space(3))) unsigned int*)l, 16, 0, 0);
}

// ---------------------------------------------------------------------------
// Kernel 1: fp16 prep + maskAdd (vectorized x4).
//   x (8192x512 f32) -> Xh (8192x512 fp16)
//   Wq|Wk|Wv -> Wqkv (1536x512 fp16); Wp -> Wpc (512x512 fp16)
// ---------------------------------------------------------------------------
__global__ void prep_kernel(const float* __restrict__ x,
                            const float* __restrict__ mask,
                            const float* __restrict__ Wq,
                            const float* __restrict__ Wk,
                            const float* __restrict__ Wv,
                            const float* __restrict__ Wp,
                            short* __restrict__ Xh,
                            short* __restrict__ Wqkv,
                            short* __restrict__ Wpc,
                            float* __restrict__ maskAdd) {
  const int NXv = MM * CC / 4;     // 1,048,576 float4 groups
  const int NWv = CC * CC / 4;     // 65,536 per weight
  const int NM = BB * TT;          // 8192
  int stride = gridDim.x * blockDim.x;
  for (int i = blockIdx.x * blockDim.x + threadIdx.x; i < NXv + 4 * NWv + NM; i += stride) {
    if (i < NXv) {
      int e = i * 4;
      float4 v = *(const float4*)(x + e);
      s16x4 h = {f2hs(v.x), f2hs(v.y), f2hs(v.z), f2hs(v.w)};
      *(s16x4*)(Xh + e) = h;
    } else if (i < NXv + 4 * NWv) {
      int wi = i - NXv;
      int wsel = wi >> 16;                 // 0=Wq 1=Wk 2=Wv 3=Wp
      int idx = wi & 65535;
      int r = idx >> 7, c = (idx & 127) << 2;
      const float* W = (wsel == 0) ? Wq : (wsel == 1) ? Wk : (wsel == 2) ? Wv : Wp;
      float4 v = *(const float4*)(W + (size_t)r * CC + c);
      s16x4 h = {f2hs(v.x), f2hs(v.y), f2hs(v.z), f2hs(v.w)};
      short* dst = (wsel < 3) ? (Wqkv + (size_t)(wsel * 512 + r) * CC + c)
                              : (Wpc + (size_t)r * CC + c);
      *(s16x4*)dst = h;
    } else {
      int mi = i - NXv - 4 * NWv;
      maskAdd[mi] = (mask[mi] == 0.f) ? -1e30f : 0.f;
    }
  }
}

// ---------------------------------------------------------------------------
// 4-phase pipelined fp16 GEMM: A[M][512] fp16 @ Bw[N][512]^T. BM=128, BK=64,
// 8 waves (2M x 4N), per-wave 64 x BN/4. Double-buffered LDS (2 blocks/CU).
// Phases over (mh,kk): {ds_read || stage-issue -> barrier -> lgkmcnt(0) ->
// setprio(1) -> MFMA -> setprio(0)}; vmcnt(0) once per K-tile.
// XOR swizzle (row&7)<<4 via pre-swizzled global source + swizzled ds_read.
// EPI==0: scatter q,k -> (B,H,T,64) fp16, v -> vt (B,H,64,T) fp16, +bias
// EPI==1: out fp32 = acc + bias
// ---------------------------------------------------------------------------
template <int BN, int EPI>
__global__ __launch_bounds__(512, 4) void gemm_kernel(
    const short* __restrict__ A, const short* __restrict__ Bw,
    const float* __restrict__ b0, const float* __restrict__ b1,
    const float* __restrict__ b2,
    short* __restrict__ qo, short* __restrict__ ko, short* __restrict__ vt,
    float* __restrict__ outp) {
  constexpr int MR = 4;
  constexpr int NR = BN / 64;          // 3 (qkv) / 2 (proj)
  constexpr int ABYT = 128 * 128;      // A tile bytes (128 rows x 64 fp16)
  constexpr int TILE = ABYT + BN * 128;
  constexpr int NT = 8;                // K=512 / 64
  constexpr int BL = BN / 64;
  __shared__ __align__(1024) char smem[2 * TILE];

  const int tid = threadIdx.x;
  const int lane = tid & 63;
  const int w = tid >> 6;              // 0..7
  const int wm = w >> 2, wn = w & 3;   // 2M x 4N
  const int l15 = lane & 15, lg = lane >> 4;
  const int lsw = (l15 & 7) << 4;      // read-side swizzle
  const int sr8 = lane >> 3;
  const int scbsw = ((lane & 7) * 16) ^ (sr8 << 4);  // pre-swizzled src col

  const int rowA = blockIdx.x * 128;
  const int rowB = blockIdx.y * BN;
  const char* Ab = (const char*)A + (size_t)(rowA + sr8) * 1024 + scbsw;
  const char* Bb = (const char*)Bw + (size_t)(rowB + sr8) * 1024 + scbsw;

  f32x4 acc[MR][NR] = {};

  auto STAGE_A = [&](char* dst, int kt) {
#pragma unroll
    for (int g = 0; g < 2; ++g) {
      int r0 = (w * 2 + g) * 8;
      gload_lds16(Ab + (size_t)r0 * 1024 + (size_t)kt * 128, dst + r0 * 128);
    }
  };
  auto STAGE_B = [&](char* dst, int kt) {
#pragma unroll
    for (int g = 0; g < BL; ++g) {
      int r0 = (w * BL + g) * 8;
      gload_lds16(Bb + (size_t)r0 * 1024 + (size_t)kt * 128, dst + ABYT + r0 * 128);
    }
  };
  auto RDA2 = [&](const char* buf, int mh, int kk, f16x8* af) {
#pragma unroll
    for (int i = 0; i < 2; ++i) {
      int row = wm * 64 + (mh * 2 + i) * 16 + l15;
      af[i] = *(const f16x8*)(buf + row * 128 + ((kk * 64 + lg * 16) ^ lsw));
    }
  };
  auto RDBk = [&](const char* buf, int kk, f16x8* bfr) {
#pragma unroll
    for (int j = 0; j < NR; ++j) {
      int row = wn * (BN / 4) + j * 16 + l15;
      bfr[j] = *(const f16x8*)(buf + ABYT + row * 128 + ((kk * 64 + lg * 16) ^ lsw));
    }
  };

  // prologue: stage tile 0, drain once
  STAGE_A(smem, 0);
  STAGE_B(smem, 0);
  asm volatile("s_waitcnt vmcnt(0)" ::: "memory");
  __builtin_amdgcn_s_barrier();

  for (int t = 0; t < NT; ++t) {
    char* bufp = smem + (t & 1) * TILE;
    char* bufn = smem + ((t + 1) & 1) * TILE;
    f16x8 af[2], bfr[NR];

#define PH(MH)                                                                \
  __builtin_amdgcn_s_barrier();                                               \
  asm volatile("s_waitcnt lgkmcnt(0)" ::: "memory");                          \
  __builtin_amdgcn_sched_barrier(0);                                          \
  __builtin_amdgcn_s_setprio(1);                                              \
  _Pragma("unroll")                                                           \
  for (int i = 0; i < 2; ++i)                                                 \
    _Pragma("unroll")                                                         \
    for (int j = 0; j < NR; ++j)                                              \
      acc[(MH) * 2 + i][j] = mfma16h(af[i], bfr[j], acc[(MH) * 2 + i][j]);    \
  __builtin_amdgcn_s_setprio(0);

    // phase 0: (mh0,kk0); issue A-stage of t+1
    RDBk(bufp, 0, bfr);
    RDA2(bufp, 0, 0, af);
    if (t + 1 < NT) STAGE_A(bufn, t + 1);
    PH(0)
    // phase 1: (mh1,kk0); issue B-stage of t+1
    RDA2(bufp, 1, 0, af);
    if (t + 1 < NT) STAGE_B(bufn, t + 1);
    PH(1)
    // phase 2: (mh1,kk1)
    RDBk(bufp, 1, bfr);
    RDA2(bufp, 1, 1, af);
    PH(1)
    // phase 3: (mh0,kk1)
    RDA2(bufp, 0, 1, af);
    PH(0)
#undef PH
    // tile end: drain own t+1 stage loads, release bufp
    asm volatile("s_waitcnt vmcnt(0)" ::: "memory");
    __builtin_amdgcn_s_barrier();
  }

  // epilogue: C row = rowA + wm*64 + m*16 + lg*4 + j, col = rowB + wn*(BN/4) + n*16 + l15
#pragma unroll
  for (int m = 0; m < MR; ++m) {
    int rbase = rowA + wm * 64 + m * 16 + lg * 4;
#pragma unroll
    for (int n = 0; n < NR; ++n) {
      int col = rowB + wn * (BN / 4) + n * 16 + l15;
#pragma unroll
      for (int j = 0; j < 4; ++j) {
        float v = acc[m][n][j];
        int r = rbase + j;
        if constexpr (EPI == 0) {
          int b = r >> 10, t = r & 1023;
          int wsel = col >> 9, c = col & 511;
          int h = c >> 6, dd = c & 63;
          int bh = b * HH + h;
          if (wsel == 0) {
            qo[((size_t)bh * TT + t) * DD + dd] = f2hs(v + b0[c]);
          } else if (wsel == 1) {
            ko[((size_t)bh * TT + t) * DD + dd] = f2hs(v + b1[c]);
          } else {
            vt[((size_t)bh * DD + dd) * TT + t] = f2hs(v + b2[c]);
          }
        } else {
          outp[(size_t)r * CC + col] = v + b0[col];
        }
      }
    }
  }
}

// ---------------------------------------------------------------------------
// Flash attention (fp16), block-causal over 8-token frames.
// Grid: (B*H)*16 q-tiles of 64 rows. 4 waves, each owns 16 q-rows.
// K,V staged in LDS (double-buffered, XOR-swizzled). Swapped QK^T.
// Output: Yh (8192x512 fp16).
// ---------------------------------------------------------------------------
__global__ __launch_bounds__(256, 2) void attn_kernel(
    const short* __restrict__ q, const short* __restrict__ k,
    const short* __restrict__ vt, const float* __restrict__ maskAdd,
    short* __restrict__ Yh) {
  const int blk = blockIdx.x;
  const int qb = blk & 15;
  const int bh = blk >> 4;
  const int b = bh >> 3, h = bh & 7;
  const int tid = threadIdx.x;
  const int lane = tid & 63;
  const int w = tid >> 6;
  const int l15 = lane & 15, lg = lane >> 4;
  const int lsw = (l15 & 7) << 4;

  __shared__ short Ks[2][64 * 64];
  __shared__ short Vs[2][64 * 64];
  __shared__ short Pl[4][16 * 64];

  const short* kbh = k + (size_t)bh * TT * DD;
  const short* vbh = vt + (size_t)bh * DD * TT;

  const int sr = lane >> 3;            // 0..7
  const int scb = (lane & 7) * 16;     // byte col
  const int ssw = sr << 4;             // (row&7)<<4 swizzle

  const int qrow = qb * 64 + w * 16 + l15;
  const short* qptr = q + ((size_t)bh * TT + qrow) * DD;
  f16x8 qf[2];
  qf[0] = *(const f16x8*)(qptr + lg * 8);
  qf[1] = *(const f16x8*)(qptr + 32 + lg * 8);

  f32x4 yacc[4] = {};
  float mrun = -1e30f, lrun = 0.f;

#pragma unroll
  for (int ph = 0; ph < 2; ++ph) {
    int row = w * 8 + ph * 32 + sr;
    gload_lds16((const char*)kbh + (size_t)row * 128 + (scb ^ ssw),
                (char*)&Ks[0][0] + (w * 8 + ph * 32) * 128);
    gload_lds16((const char*)vbh + (size_t)row * 2048 + (scb ^ ssw),
                (char*)&Vs[0][0] + (w * 8 + ph * 32) * 128);
  }
  __syncthreads();

  int buf = 0;
  for (int jt = 0; jt <= qb; ++jt) {
    if (jt < qb) {
      int nt = jt + 1;
#pragma unroll
      for (int ph = 0; ph < 2; ++ph) {
        int row = w * 8 + ph * 32 + sr;
        gload_lds16((const char*)kbh + (size_t)(nt * 64 + row) * 128 + (scb ^ ssw),
                    (char*)&Ks[buf ^ 1][0] + (w * 8 + ph * 32) * 128);
        gload_lds16((const char*)vbh + (size_t)row * 2048 + nt * 128 + (scb ^ ssw),
                    (char*)&Vs[buf ^ 1][0] + (w * 8 + ph * 32) * 128);
      }
    }
    f32x4 mav[4];
#pragma unroll
    for (int n = 0; n < 4; ++n)
      mav[n] = *(const f32x4*)(maskAdd + (size_t)b * TT + jt * 64 + n * 16 + lg * 4);

    f32x4 sacc[4] = {};
#pragma unroll
    for (int c = 0; c < 2; ++c) {
      f16x8 qc = qf[c];
#pragma unroll
      for (int n = 0; n < 4; ++n) {
        int krow = n * 16 + l15;
        const f16x8 kf = *(const f16x8*)((const char*)&Ks[buf][0] + krow * 128 + ((c * 64 + lg * 16) ^ lsw));
        sacc[n] = mfma16h(kf, qc, sacc[n]);
      }
    }
    const int qloc8 = (w * 16 + l15) >> 3;
#pragma unroll
    for (int n = 0; n < 4; ++n)
#pragma unroll
      for (int jj = 0; jj < 4; ++jj) {
        float s = sacc[n][jj] * 0.125f + mav[n][jj];
        if (jt == qb) {
          int kloc = n * 16 + lg * 4 + jj;
          if ((kloc >> 3) > qloc8) s = -1e30f;
        }
        sacc[n][jj] = s;
      }
    float pm = sacc[0][0];
#pragma unroll
    for (int n = 0; n < 4; ++n)
#pragma unroll
      for (int jj = 0; jj < 4; ++jj) pm = fmaxf(pm, sacc[n][jj]);
    pm = fmaxf(pm, __shfl_xor(pm, 16));
    pm = fmaxf(pm, __shfl_xor(pm, 32));
    float mnew = fmaxf(mrun, pm);
    float alpha = __expf(mrun - mnew);
    mrun = mnew;
    float psum = 0.f;
#pragma unroll
    for (int n = 0; n < 4; ++n) {
      float p0 = __expf(sacc[n][0] - mrun);
      float p1 = __expf(sacc[n][1] - mrun);
      float p2 = __expf(sacc[n][2] - mrun);
      float p3 = __expf(sacc[n][3] - mrun);
      psum += (p0 + p1) + (p2 + p3);
      uint2 pw;
      pw.x = (unsigned)(unsigned short)f2hs(p0) | ((unsigned)(unsigned short)f2hs(p1) << 16);
      pw.y = (unsigned)(unsigned short)f2hs(p2) | ((unsigned)(unsigned short)f2hs(p3) << 16);
      *(uint2*)((char*)&Pl[w][0] + l15 * 128 + ((n * 32 + lg * 8) ^ lsw)) = pw;
    }
    psum += __shfl_xor(psum, 16);
    psum += __shfl_xor(psum, 32);
    lrun = lrun * alpha + psum;
    float ab[4];
#pragma unroll
    for (int jj = 0; jj < 4; ++jj) ab[jj] = __shfl(alpha, lg * 4 + jj);
#pragma unroll
    for (int dt = 0; dt < 4; ++dt)
#pragma unroll
      for (int jj = 0; jj < 4; ++jj) yacc[dt][jj] *= ab[jj];
#pragma unroll
    for (int c = 0; c < 2; ++c) {
      const f16x8 pa = *(const f16x8*)((const char*)&Pl[w][0] + l15 * 128 + ((c * 64 + lg * 16) ^ lsw));
#pragma unroll
      for (int dt = 0; dt < 4; ++dt) {
        int vrow = dt * 16 + l15;
        const f16x8 vf = *(const f16x8*)((const char*)&Vs[buf][0] + vrow * 128 + ((c * 64 + lg * 16) ^ lsw));
        yacc[dt] = mfma16h(pa, vf, yacc[dt]);
      }
    }
    __syncthreads();
    buf ^= 1;
  }

  float lb[4];
#pragma unroll
  for (int jj = 0; jj < 4; ++jj) lb[jj] = 1.f / __shfl(lrun, lg * 4 + jj);
#pragma unroll
  for (int dt = 0; dt < 4; ++dt) {
    int col = h * DD + dt * 16 + l15;
#pragma unroll
    for (int jj = 0; jj < 4; ++jj) {
      int row = b * TT + qb * 64 + w * 16 + lg * 4 + jj;
      float y = yacc[dt][jj] * lb[jj];
      Yh[(size_t)row * CC + col] = f2hs(y);
    }
  }
}

// ---------------------------------------------------------------------------
extern "C" void kernel_launch(void* const* d_in, const int* in_sizes, int n_in,
                              void* d_out, int out_size, void* d_ws, size_t ws_size,
                              hipStream_t stream) {
  const float* x    = (const float*)d_in[0];
  const float* mask = (const float*)d_in[1];
  const float* Wq   = (const float*)d_in[2];
  const float* bq   = (const float*)d_in[3];
  const float* Wk   = (const float*)d_in[4];
  const float* bk   = (const float*)d_in[5];
  const float* Wv   = (const float*)d_in[6];
  const float* bv   = (const float*)d_in[7];
  const float* Wp   = (const float*)d_in[8];
  const float* bp   = (const float*)d_in[9];
  float* out = (float*)d_out;

  char* ws = (char*)d_ws;
  short* Xh   = (short*)(ws);                          // 8 MB
  short* Wqkv = (short*)(ws + (size_t)8 * 1048576);    // 1.5 MB
  short* Wpc  = (short*)(ws + (size_t)10 * 1048576);   // 0.5 MB
  short* qo   = (short*)(ws + (size_t)11 * 1048576);   // 8 MB
  short* ko   = (short*)(ws + (size_t)19 * 1048576);   // 8 MB
  short* vt   = (short*)(ws + (size_t)27 * 1048576);   // 8 MB
  short* Yh   = (short*)(ws + (size_t)35 * 1048576);   // 8 MB
  float* maskAdd = (float*)(ws + (size_t)43 * 1048576); // 32 KB

  prep_kernel<<<2048, 256, 0, stream>>>(x, mask, Wq, Wk, Wv, Wp, Xh, Wqkv, Wpc, maskAdd);

  // QKV: M=8192/128=64, N=1536/192=8 -> 512 blocks = 2/CU
  gemm_kernel<192, 0><<<dim3(64, 8), 512, 0, stream>>>(
      Xh, Wqkv, bq, bk, bv, qo, ko, vt, nullptr);

  attn_kernel<<<dim3(64 * 16), 256, 0, stream>>>(qo, ko, vt, maskAdd, Yh);

  // proj: M=8192/128=64, N=512/128=4 -> 256 blocks
  gemm_kernel<128, 1><<<dim3(64, 4), 512, 0, stream>>>(
      Yh, Wpc, bp, nullptr, nullptr, nullptr, nullptr, nullptr, out);
}

// Round 6
// 81.039 us; speedup vs baseline: 2.4865x; 1.0971x over previous
//
#include <hip/hip_runtime.h>
#include <cstdint>
#include <cstddef>

// Problem constants
#define BB 8
#define TT 1024
#define CC 512
#define HH 8
#define DD 64
#define MM (BB*TT)     // 8192 rows

typedef short s16x4 __attribute__((ext_vector_type(4)));
typedef _Float16 f16x8 __attribute__((ext_vector_type(8)));
typedef float f32x4  __attribute__((ext_vector_type(4)));

__device__ __forceinline__ short f2hs(float f) {
  _Float16 h = (_Float16)f;
  return __builtin_bit_cast(short, h);
}

__device__ __forceinline__ f32x4 mfma16h(f16x8 a, f16x8 b, f32x4 c) {
  return __builtin_amdgcn_mfma_f32_16x16x32_f16(a, b, c, 0, 0, 0);
}

__device__ __forceinline__ void gload_lds16(const void* g, void* l) {
  __builtin_amdgcn_global_load_lds(
      (const __attribute__((address_space(1))) unsigned int*)g,
      (__attribute__((address_space(3))) unsigned int*)l, 16, 0, 0);
}

// ---------------------------------------------------------------------------
// Kernel 1: fp16 prep + maskAdd (vectorized x4).
// ---------------------------------------------------------------------------
__global__ void prep_kernel(const float* __restrict__ x,
                            const float* __restrict__ mask,
                            const float* __restrict__ Wq,
                            const float* __restrict__ Wk,
                            const float* __restrict__ Wv,
                            const float* __restrict__ Wp,
                            short* __restrict__ Xh,
                            short* __restrict__ Wqkv,
                            short* __restrict__ Wpc,
                            float* __restrict__ maskAdd) {
  const int NXv = MM * CC / 4;     // 1,048,576 float4 groups
  const int NWv = CC * CC / 4;     // 65,536 per weight
  const int NM = BB * TT;          // 8192
  int stride = gridDim.x * blockDim.x;
  for (int i = blockIdx.x * blockDim.x + threadIdx.x; i < NXv + 4 * NWv + NM; i += stride) {
    if (i < NXv) {
      int e = i * 4;
      float4 v = *(const float4*)(x + e);
      s16x4 h = {f2hs(v.x), f2hs(v.y), f2hs(v.z), f2hs(v.w)};
      *(s16x4*)(Xh + e) = h;
    } else if (i < NXv + 4 * NWv) {
      int wi = i - NXv;
      int wsel = wi >> 16;                 // 0=Wq 1=Wk 2=Wv 3=Wp
      int idx = wi & 65535;
      int r = idx >> 7, c = (idx & 127) << 2;
      const float* W = (wsel == 0) ? Wq : (wsel == 1) ? Wk : (wsel == 2) ? Wv : Wp;
      float4 v = *(const float4*)(W + (size_t)r * CC + c);
      s16x4 h = {f2hs(v.x), f2hs(v.y), f2hs(v.z), f2hs(v.w)};
      short* dst = (wsel < 3) ? (Wqkv + (size_t)(wsel * 512 + r) * CC + c)
                              : (Wpc + (size_t)r * CC + c);
      *(s16x4*)dst = h;
    } else {
      int mi = i - NXv - 4 * NWv;
      maskAdd[mi] = (mask[mi] == 0.f) ? -1e30f : 0.f;
    }
  }
}

// ---------------------------------------------------------------------------
// 4-phase pipelined fp16 GEMM: A[M][512] fp16 @ Bw[N][512]^T. BM=128, BK=64,
// 8 waves (2M x 4N). Double-buffered LDS. (unchanged from round 5)
// ---------------------------------------------------------------------------
template <int BN, int EPI>
__global__ __launch_bounds__(512, 4) void gemm_kernel(
    const short* __restrict__ A, const short* __restrict__ Bw,
    const float* __restrict__ b0, const float* __restrict__ b1,
    const float* __restrict__ b2,
    short* __restrict__ qo, short* __restrict__ ko, short* __restrict__ vt,
    float* __restrict__ outp) {
  constexpr int MR = 4;
  constexpr int NR = BN / 64;
  constexpr int ABYT = 128 * 128;
  constexpr int TILE = ABYT + BN * 128;
  constexpr int NT = 8;                // K=512 / 64
  constexpr int BL = BN / 64;
  __shared__ __align__(1024) char smem[2 * TILE];

  const int tid = threadIdx.x;
  const int lane = tid & 63;
  const int w = tid >> 6;
  const int wm = w >> 2, wn = w & 3;
  const int l15 = lane & 15, lg = lane >> 4;
  const int lsw = (l15 & 7) << 4;
  const int sr8 = lane >> 3;
  const int scbsw = ((lane & 7) * 16) ^ (sr8 << 4);

  const int rowA = blockIdx.x * 128;
  const int rowB = blockIdx.y * BN;
  const char* Ab = (const char*)A + (size_t)(rowA + sr8) * 1024 + scbsw;
  const char* Bb = (const char*)Bw + (size_t)(rowB + sr8) * 1024 + scbsw;

  f32x4 acc[MR][NR] = {};

  auto STAGE_A = [&](char* dst, int kt) {
#pragma unroll
    for (int g = 0; g < 2; ++g) {
      int r0 = (w * 2 + g) * 8;
      gload_lds16(Ab + (size_t)r0 * 1024 + (size_t)kt * 128, dst + r0 * 128);
    }
  };
  auto STAGE_B = [&](char* dst, int kt) {
#pragma unroll
    for (int g = 0; g < BL; ++g) {
      int r0 = (w * BL + g) * 8;
      gload_lds16(Bb + (size_t)r0 * 1024 + (size_t)kt * 128, dst + ABYT + r0 * 128);
    }
  };
  auto RDA2 = [&](const char* buf, int mh, int kk, f16x8* af) {
#pragma unroll
    for (int i = 0; i < 2; ++i) {
      int row = wm * 64 + (mh * 2 + i) * 16 + l15;
      af[i] = *(const f16x8*)(buf + row * 128 + ((kk * 64 + lg * 16) ^ lsw));
    }
  };
  auto RDBk = [&](const char* buf, int kk, f16x8* bfr) {
#pragma unroll
    for (int j = 0; j < NR; ++j) {
      int row = wn * (BN / 4) + j * 16 + l15;
      bfr[j] = *(const f16x8*)(buf + ABYT + row * 128 + ((kk * 64 + lg * 16) ^ lsw));
    }
  };

  STAGE_A(smem, 0);
  STAGE_B(smem, 0);
  asm volatile("s_waitcnt vmcnt(0)" ::: "memory");
  __builtin_amdgcn_s_barrier();

  for (int t = 0; t < NT; ++t) {
    char* bufp = smem + (t & 1) * TILE;
    char* bufn = smem + ((t + 1) & 1) * TILE;
    f16x8 af[2], bfr[NR];

#define PH(MH)                                                                \
  __builtin_amdgcn_s_barrier();                                               \
  asm volatile("s_waitcnt lgkmcnt(0)" ::: "memory");                          \
  __builtin_amdgcn_sched_barrier(0);                                          \
  __builtin_amdgcn_s_setprio(1);                                              \
  _Pragma("unroll")                                                           \
  for (int i = 0; i < 2; ++i)                                                 \
    _Pragma("unroll")                                                         \
    for (int j = 0; j < NR; ++j)                                              \
      acc[(MH) * 2 + i][j] = mfma16h(af[i], bfr[j], acc[(MH) * 2 + i][j]);    \
  __builtin_amdgcn_s_setprio(0);

    RDBk(bufp, 0, bfr);
    RDA2(bufp, 0, 0, af);
    if (t + 1 < NT) STAGE_A(bufn, t + 1);
    PH(0)
    RDA2(bufp, 1, 0, af);
    if (t + 1 < NT) STAGE_B(bufn, t + 1);
    PH(1)
    RDBk(bufp, 1, bfr);
    RDA2(bufp, 1, 1, af);
    PH(1)
    RDA2(bufp, 0, 1, af);
    PH(0)
#undef PH
    asm volatile("s_waitcnt vmcnt(0)" ::: "memory");
    __builtin_amdgcn_s_barrier();
  }

#pragma unroll
  for (int m = 0; m < MR; ++m) {
    int rbase = rowA + wm * 64 + m * 16 + lg * 4;
#pragma unroll
    for (int n = 0; n < NR; ++n) {
      int col = rowB + wn * (BN / 4) + n * 16 + l15;
#pragma unroll
      for (int j = 0; j < 4; ++j) {
        float v = acc[m][n][j];
        int r = rbase + j;
        if constexpr (EPI == 0) {
          int b = r >> 10, t = r & 1023;
          int wsel = col >> 9, c = col & 511;
          int h = c >> 6, dd = c & 63;
          int bh = b * HH + h;
          if (wsel == 0) {
            qo[((size_t)bh * TT + t) * DD + dd] = f2hs(v + b0[c]);
          } else if (wsel == 1) {
            ko[((size_t)bh * TT + t) * DD + dd] = f2hs(v + b1[c]);
          } else {
            vt[((size_t)bh * DD + dd) * TT + t] = f2hs(v + b2[c]);
          }
        } else {
          outp[(size_t)r * CC + col] = v + b0[col];
        }
      }
    }
  }
}

// ---------------------------------------------------------------------------
// Flash attention v3 (fp16), block-causal over 8-token frames.
// Grid: 64 bh x 8 pairs = 512 blocks, 8 waves (512 thr). Block owns q-tile
// PAIR (qbA=8+p, qbB=7-p) -> exactly 17 compute-units/block, 34/CU: perfectly
// load-balanced. Waves 0-3 compute tile A rows, waves 4-7 tile B rows; one
// shared K/V LDS stage per jt serves both. Double-buffered, XOR-swizzled.
// Swapped QK^T (softmax lane-local per q). Output Yh (8192x512 fp16).
// ---------------------------------------------------------------------------
__global__ __launch_bounds__(512, 2) void attn_kernel(
    const short* __restrict__ q, const short* __restrict__ k,
    const short* __restrict__ vt, const float* __restrict__ maskAdd,
    short* __restrict__ Yh) {
  const int blk = blockIdx.x;
  const int p = blk & 7;
  const int bh = blk >> 3;
  const int b = bh >> 3, h = bh & 7;
  const int qbA = 8 + p;               // loop length qbA+1 = 9..16
  const int qbB = 7 - p;
  const int tid = threadIdx.x;
  const int lane = tid & 63;
  const int w = tid >> 6;              // 0..7
  const int wloc = w & 3;
  const int qtile = (w < 4) ? qbA : qbB;
  const int l15 = lane & 15, lg = lane >> 4;
  const int lsw = (l15 & 7) << 4;

  __shared__ short Ks[2][64 * 64];
  __shared__ short Vs[2][64 * 64];
  __shared__ short Pl[8][16 * 64];

  const short* kbh = k + (size_t)bh * TT * DD;
  const short* vbh = vt + (size_t)bh * DD * TT;

  // staging: 512 threads cover 64 rows x 128B, one 16B chunk each
  const int srow = tid >> 3;                           // 0..63
  const int scb = ((tid & 7) * 16) ^ ((srow & 7) << 4);  // pre-swizzled col

  const int qrow = qtile * 64 + wloc * 16 + l15;
  const short* qptr = q + ((size_t)bh * TT + qrow) * DD;
  f16x8 qf0 = *(const f16x8*)(qptr + lg * 8);
  f16x8 qf1 = *(const f16x8*)(qptr + 32 + lg * 8);

  f32x4 yacc[4] = {};
  float mrun = -1e30f, lrun = 0.f;

  // prologue stage of tile 0
  gload_lds16((const char*)kbh + (size_t)srow * 128 + scb,
              (char*)&Ks[0][0] + srow * 128);
  gload_lds16((const char*)vbh + (size_t)srow * 2048 + scb,
              (char*)&Vs[0][0] + srow * 128);
  __syncthreads();

  int buf = 0;
  for (int jt = 0; jt <= qbA; ++jt) {
    // async prefetch of next K/V tile
    if (jt < qbA) {
      int nt = jt + 1;
      gload_lds16((const char*)kbh + (size_t)(nt * 64 + srow) * 128 + scb,
                  (char*)&Ks[buf ^ 1][0] + srow * 128);
      gload_lds16((const char*)vbh + (size_t)srow * 2048 + nt * 128 + scb,
                  (char*)&Vs[buf ^ 1][0] + srow * 128);
    }
    if (jt <= qtile) {   // wave-uniform: is this wave's q-tile active?
      f32x4 mav[4];
#pragma unroll
      for (int n = 0; n < 4; ++n)
        mav[n] = *(const f32x4*)(maskAdd + (size_t)b * TT + jt * 64 + n * 16 + lg * 4);

      // QK^T swapped: sacc[n][jj] = S[k = n*16+lg*4+jj][q = l15]
      f32x4 sacc[4] = {};
      __builtin_amdgcn_s_setprio(1);
#pragma unroll
      for (int c = 0; c < 2; ++c) {
        f16x8 qc = (c == 0) ? qf0 : qf1;
#pragma unroll
        for (int n = 0; n < 4; ++n) {
          int krow = n * 16 + l15;
          const f16x8 kf = *(const f16x8*)((const char*)&Ks[buf][0] + krow * 128 + ((c * 64 + lg * 16) ^ lsw));
          sacc[n] = mfma16h(kf, qc, sacc[n]);
        }
      }
      __builtin_amdgcn_s_setprio(0);
      const int qloc8 = (wloc * 16 + l15) >> 3;
#pragma unroll
      for (int n = 0; n < 4; ++n)
#pragma unroll
        for (int jj = 0; jj < 4; ++jj) {
          float s = sacc[n][jj] * 0.125f + mav[n][jj];
          if (jt == qtile) {
            int kloc = n * 16 + lg * 4 + jj;
            if ((kloc >> 3) > qloc8) s = -1e30f;
          }
          sacc[n][jj] = s;
        }
      float pm = sacc[0][0];
#pragma unroll
      for (int n = 0; n < 4; ++n)
#pragma unroll
        for (int jj = 0; jj < 4; ++jj) pm = fmaxf(pm, sacc[n][jj]);
      pm = fmaxf(pm, __shfl_xor(pm, 16));
      pm = fmaxf(pm, __shfl_xor(pm, 32));
      float mnew = fmaxf(mrun, pm);
      float alpha = __expf(mrun - mnew);
      mrun = mnew;
      float psum = 0.f;
#pragma unroll
      for (int n = 0; n < 4; ++n) {
        float p0 = __expf(sacc[n][0] - mrun);
        float p1 = __expf(sacc[n][1] - mrun);
        float p2 = __expf(sacc[n][2] - mrun);
        float p3 = __expf(sacc[n][3] - mrun);
        psum += (p0 + p1) + (p2 + p3);
        uint2 pw;
        pw.x = (unsigned)(unsigned short)f2hs(p0) | ((unsigned)(unsigned short)f2hs(p1) << 16);
        pw.y = (unsigned)(unsigned short)f2hs(p2) | ((unsigned)(unsigned short)f2hs(p3) << 16);
        *(uint2*)((char*)&Pl[w][0] + l15 * 128 + ((n * 32 + lg * 8) ^ lsw)) = pw;
      }
      psum += __shfl_xor(psum, 16);
      psum += __shfl_xor(psum, 32);
      lrun = lrun * alpha + psum;
      float ab[4];
#pragma unroll
      for (int jj = 0; jj < 4; ++jj) ab[jj] = __shfl(alpha, lg * 4 + jj);
#pragma unroll
      for (int dt = 0; dt < 4; ++dt)
#pragma unroll
        for (int jj = 0; jj < 4; ++jj) yacc[dt][jj] *= ab[jj];
      // PV
      __builtin_amdgcn_s_setprio(1);
#pragma unroll
      for (int c = 0; c < 2; ++c) {
        const f16x8 pa = *(const f16x8*)((const char*)&Pl[w][0] + l15 * 128 + ((c * 64 + lg * 16) ^ lsw));
#pragma unroll
        for (int dt = 0; dt < 4; ++dt) {
          int vrow = dt * 16 + l15;
          const f16x8 vf = *(const f16x8*)((const char*)&Vs[buf][0] + vrow * 128 + ((c * 64 + lg * 16) ^ lsw));
          yacc[dt] = mfma16h(pa, vf, yacc[dt]);
        }
      }
      __builtin_amdgcn_s_setprio(0);
    }
    __syncthreads();   // drains prefetch vmcnt + all waves' LDS reads
    buf ^= 1;
  }

  float lb[4];
#pragma unroll
  for (int jj = 0; jj < 4; ++jj) lb[jj] = 1.f / __shfl(lrun, lg * 4 + jj);
#pragma unroll
  for (int dt = 0; dt < 4; ++dt) {
    int col = h * DD + dt * 16 + l15;
#pragma unroll
    for (int jj = 0; jj < 4; ++jj) {
      int row = b * TT + qtile * 64 + wloc * 16 + lg * 4 + jj;
      float y = yacc[dt][jj] * lb[jj];
      Yh[(size_t)row * CC + col] = f2hs(y);
    }
  }
}

// ---------------------------------------------------------------------------
extern "C" void kernel_launch(void* const* d_in, const int* in_sizes, int n_in,
                              void* d_out, int out_size, void* d_ws, size_t ws_size,
                              hipStream_t stream) {
  const float* x    = (const float*)d_in[0];
  const float* mask = (const float*)d_in[1];
  const float* Wq   = (const float*)d_in[2];
  const float* bq   = (const float*)d_in[3];
  const float* Wk   = (const float*)d_in[4];
  const float* bk   = (const float*)d_in[5];
  const float* Wv   = (const float*)d_in[6];
  const float* bv   = (const float*)d_in[7];
  const float* Wp   = (const float*)d_in[8];
  const float* bp   = (const float*)d_in[9];
  float* out = (float*)d_out;

  char* ws = (char*)d_ws;
  short* Xh   = (short*)(ws);                          // 8 MB
  short* Wqkv = (short*)(ws + (size_t)8 * 1048576);    // 1.5 MB
  short* Wpc  = (short*)(ws + (size_t)10 * 1048576);   // 0.5 MB
  short* qo   = (short*)(ws + (size_t)11 * 1048576);   // 8 MB
  short* ko   = (short*)(ws + (size_t)19 * 1048576);   // 8 MB
  short* vt   = (short*)(ws + (size_t)27 * 1048576);   // 8 MB
  short* Yh   = (short*)(ws + (size_t)35 * 1048576);   // 8 MB
  float* maskAdd = (float*)(ws + (size_t)43 * 1048576); // 32 KB

  prep_kernel<<<2048, 256, 0, stream>>>(x, mask, Wq, Wk, Wv, Wp, Xh, Wqkv, Wpc, maskAdd);

  // QKV: M=8192/128=64, N=1536/192=8 -> 512 blocks = 2/CU
  gemm_kernel<192, 0><<<dim3(64, 8), 512, 0, stream>>>(
      Xh, Wqkv, bq, bk, bv, qo, ko, vt, nullptr);

  // attn: 64 bh x 8 pairs = 512 blocks, balanced 17 units each
  attn_kernel<<<dim3(512), 512, 0, stream>>>(qo, ko, vt, maskAdd, Yh);

  // proj: M=8192/128=64, N=512/128=4 -> 256 blocks
  gemm_kernel<128, 1><<<dim3(64, 4), 512, 0, stream>>>(
      Yh, Wpc, bp, nullptr, nullptr, nullptr, nullptr, nullptr, out);
}

// Round 7
// 74.110 us; speedup vs baseline: 2.7189x; 1.0935x over previous
//
#include <hip/hip_runtime.h>
#include <cstdint>
#include <cstddef>

// Problem constants
#define BB 8
#define TT 1024
#define CC 512
#define HH 8
#define DD 64
#define MM (BB*TT)     // 8192 rows

typedef short s16x4 __attribute__((ext_vector_type(4)));
typedef _Float16 f16x8 __attribute__((ext_vector_type(8)));
typedef _Float16 f16x2 __attribute__((ext_vector_type(2)));
typedef float f32x4  __attribute__((ext_vector_type(4)));

__device__ __forceinline__ short f2hs(float f) {
  _Float16 h = (_Float16)f;
  return __builtin_bit_cast(short, h);
}

__device__ __forceinline__ f32x4 mfma16h(f16x8 a, f16x8 b, f32x4 c) {
  return __builtin_amdgcn_mfma_f32_16x16x32_f16(a, b, c, 0, 0, 0);
}

__device__ __forceinline__ void gload_lds16(const void* g, void* l) {
  __builtin_amdgcn_global_load_lds(
      (const __attribute__((address_space(1))) unsigned int*)g,
      (__attribute__((address_space(3))) unsigned int*)l, 16, 0, 0);
}

// ---------------------------------------------------------------------------
// Kernel 1: fp16 prep + maskAdd (vectorized x4).
// ---------------------------------------------------------------------------
__global__ void prep_kernel(const float* __restrict__ x,
                            const float* __restrict__ mask,
                            const float* __restrict__ Wq,
                            const float* __restrict__ Wk,
                            const float* __restrict__ Wv,
                            const float* __restrict__ Wp,
                            short* __restrict__ Xh,
                            short* __restrict__ Wqkv,
                            short* __restrict__ Wpc,
                            float* __restrict__ maskAdd) {
  const int NXv = MM * CC / 4;     // 1,048,576 float4 groups
  const int NWv = CC * CC / 4;     // 65,536 per weight
  const int NM = BB * TT;          // 8192
  int stride = gridDim.x * blockDim.x;
  for (int i = blockIdx.x * blockDim.x + threadIdx.x; i < NXv + 4 * NWv + NM; i += stride) {
    if (i < NXv) {
      int e = i * 4;
      float4 v = *(const float4*)(x + e);
      s16x4 h = {f2hs(v.x), f2hs(v.y), f2hs(v.z), f2hs(v.w)};
      *(s16x4*)(Xh + e) = h;
    } else if (i < NXv + 4 * NWv) {
      int wi = i - NXv;
      int wsel = wi >> 16;                 // 0=Wq 1=Wk 2=Wv 3=Wp
      int idx = wi & 65535;
      int r = idx >> 7, c = (idx & 127) << 2;
      const float* W = (wsel == 0) ? Wq : (wsel == 1) ? Wk : (wsel == 2) ? Wv : Wp;
      float4 v = *(const float4*)(W + (size_t)r * CC + c);
      s16x4 h = {f2hs(v.x), f2hs(v.y), f2hs(v.z), f2hs(v.w)};
      short* dst = (wsel < 3) ? (Wqkv + (size_t)(wsel * 512 + r) * CC + c)
                              : (Wpc + (size_t)r * CC + c);
      *(s16x4*)dst = h;
    } else {
      int mi = i - NXv - 4 * NWv;
      maskAdd[mi] = (mask[mi] == 0.f) ? -1e30f : 0.f;
    }
  }
}

// ---------------------------------------------------------------------------
// 4-phase pipelined fp16 GEMM: A[M][512] fp16 @ Bw[N][512]^T. BM=128, BK=64,
// 8 waves (2M x 4N). Double-buffered LDS.
// EPI==0: scatter q (pre-scaled by 1/8!), k -> (B,H,T,64); v -> vt (B,H,64,T)
// EPI==1: out fp32 = acc + bias
// ---------------------------------------------------------------------------
template <int BN, int EPI>
__global__ __launch_bounds__(512, 4) void gemm_kernel(
    const short* __restrict__ A, const short* __restrict__ Bw,
    const float* __restrict__ b0, const float* __restrict__ b1,
    const float* __restrict__ b2,
    short* __restrict__ qo, short* __restrict__ ko, short* __restrict__ vt,
    float* __restrict__ outp) {
  constexpr int MR = 4;
  constexpr int NR = BN / 64;
  constexpr int ABYT = 128 * 128;
  constexpr int TILE = ABYT + BN * 128;
  constexpr int NT = 8;                // K=512 / 64
  constexpr int BL = BN / 64;
  __shared__ __align__(1024) char smem[2 * TILE];

  const int tid = threadIdx.x;
  const int lane = tid & 63;
  const int w = tid >> 6;
  const int wm = w >> 2, wn = w & 3;
  const int l15 = lane & 15, lg = lane >> 4;
  const int lsw = (l15 & 7) << 4;
  const int sr8 = lane >> 3;
  const int scbsw = ((lane & 7) * 16) ^ (sr8 << 4);

  const int rowA = blockIdx.x * 128;
  const int rowB = blockIdx.y * BN;
  const char* Ab = (const char*)A + (size_t)(rowA + sr8) * 1024 + scbsw;
  const char* Bb = (const char*)Bw + (size_t)(rowB + sr8) * 1024 + scbsw;

  f32x4 acc[MR][NR] = {};

  auto STAGE_A = [&](char* dst, int kt) {
#pragma unroll
    for (int g = 0; g < 2; ++g) {
      int r0 = (w * 2 + g) * 8;
      gload_lds16(Ab + (size_t)r0 * 1024 + (size_t)kt * 128, dst + r0 * 128);
    }
  };
  auto STAGE_B = [&](char* dst, int kt) {
#pragma unroll
    for (int g = 0; g < BL; ++g) {
      int r0 = (w * BL + g) * 8;
      gload_lds16(Bb + (size_t)r0 * 1024 + (size_t)kt * 128, dst + ABYT + r0 * 128);
    }
  };
  auto RDA2 = [&](const char* buf, int mh, int kk, f16x8* af) {
#pragma unroll
    for (int i = 0; i < 2; ++i) {
      int row = wm * 64 + (mh * 2 + i) * 16 + l15;
      af[i] = *(const f16x8*)(buf + row * 128 + ((kk * 64 + lg * 16) ^ lsw));
    }
  };
  auto RDBk = [&](const char* buf, int kk, f16x8* bfr) {
#pragma unroll
    for (int j = 0; j < NR; ++j) {
      int row = wn * (BN / 4) + j * 16 + l15;
      bfr[j] = *(const f16x8*)(buf + ABYT + row * 128 + ((kk * 64 + lg * 16) ^ lsw));
    }
  };

  STAGE_A(smem, 0);
  STAGE_B(smem, 0);
  asm volatile("s_waitcnt vmcnt(0)" ::: "memory");
  __builtin_amdgcn_s_barrier();

  for (int t = 0; t < NT; ++t) {
    char* bufp = smem + (t & 1) * TILE;
    char* bufn = smem + ((t + 1) & 1) * TILE;
    f16x8 af[2], bfr[NR];

#define PH(MH)                                                                \
  __builtin_amdgcn_s_barrier();                                               \
  asm volatile("s_waitcnt lgkmcnt(0)" ::: "memory");                          \
  __builtin_amdgcn_sched_barrier(0);                                          \
  __builtin_amdgcn_s_setprio(1);                                              \
  _Pragma("unroll")                                                           \
  for (int i = 0; i < 2; ++i)                                                 \
    _Pragma("unroll")                                                         \
    for (int j = 0; j < NR; ++j)                                              \
      acc[(MH) * 2 + i][j] = mfma16h(af[i], bfr[j], acc[(MH) * 2 + i][j]);    \
  __builtin_amdgcn_s_setprio(0);

    RDBk(bufp, 0, bfr);
    RDA2(bufp, 0, 0, af);
    if (t + 1 < NT) STAGE_A(bufn, t + 1);
    PH(0)
    RDA2(bufp, 1, 0, af);
    if (t + 1 < NT) STAGE_B(bufn, t + 1);
    PH(1)
    RDBk(bufp, 1, bfr);
    RDA2(bufp, 1, 1, af);
    PH(1)
    RDA2(bufp, 0, 1, af);
    PH(0)
#undef PH
    asm volatile("s_waitcnt vmcnt(0)" ::: "memory");
    __builtin_amdgcn_s_barrier();
  }

#pragma unroll
  for (int m = 0; m < MR; ++m) {
    int rbase = rowA + wm * 64 + m * 16 + lg * 4;
#pragma unroll
    for (int n = 0; n < NR; ++n) {
      int col = rowB + wn * (BN / 4) + n * 16 + l15;
#pragma unroll
      for (int j = 0; j < 4; ++j) {
        float v = acc[m][n][j];
        int r = rbase + j;
        if constexpr (EPI == 0) {
          int b = r >> 10, t = r & 1023;
          int wsel = col >> 9, c = col & 511;
          int h = c >> 6, dd = c & 63;
          int bh = b * HH + h;
          if (wsel == 0) {
            // q pre-scaled by 1/sqrt(d) so attention skips the scale
            qo[((size_t)bh * TT + t) * DD + dd] = f2hs((v + b0[c]) * 0.125f);
          } else if (wsel == 1) {
            ko[((size_t)bh * TT + t) * DD + dd] = f2hs(v + b1[c]);
          } else {
            vt[((size_t)bh * DD + dd) * TT + t] = f2hs(v + b2[c]);
          }
        } else {
          outp[(size_t)r * CC + col] = v + b0[col];
        }
      }
    }
  }
}

// ---------------------------------------------------------------------------
// Flash attention v4 (fp16), block-causal over 8-token frames.
// Grid: 64 bh x 8 pairs = 512 blocks, 8 waves. Block owns q-tile pair
// (qbA=8+p, qbB=7-p) = 17 units/block (balanced). Waves 0-3 tile A, 4-7
// tile B; shared K/V LDS stage. Softmax slimmed: mask via MFMA C-init,
// scale folded into q, defer-max (THR=8), packed cvt, max3 tree.
// ---------------------------------------------------------------------------
__global__ __launch_bounds__(512, 2) void attn_kernel(
    const short* __restrict__ q, const short* __restrict__ k,
    const short* __restrict__ vt, const float* __restrict__ maskAdd,
    short* __restrict__ Yh) {
  const int blk = blockIdx.x;
  const int p = blk & 7;
  const int bh = blk >> 3;
  const int b = bh >> 3, h = bh & 7;
  const int qbA = 8 + p;
  const int qbB = 7 - p;
  const int tid = threadIdx.x;
  const int lane = tid & 63;
  const int w = tid >> 6;
  const int wloc = w & 3;
  const int qtile = (w < 4) ? qbA : qbB;
  const int l15 = lane & 15, lg = lane >> 4;
  const int lsw = (l15 & 7) << 4;

  __shared__ short Ks[2][64 * 64];
  __shared__ short Vs[2][64 * 64];
  __shared__ short Pl[8][16 * 64];

  const short* kbh = k + (size_t)bh * TT * DD;
  const short* vbh = vt + (size_t)bh * DD * TT;

  const int srow = tid >> 3;                           // 0..63
  const int scb = ((tid & 7) * 16) ^ ((srow & 7) << 4);  // pre-swizzled col

  const int qrow = qtile * 64 + wloc * 16 + l15;
  const short* qptr = q + ((size_t)bh * TT + qrow) * DD;
  f16x8 qf0 = *(const f16x8*)(qptr + lg * 8);
  f16x8 qf1 = *(const f16x8*)(qptr + 32 + lg * 8);

  f32x4 yacc[4] = {};
  float mrun = -1e30f, lrun = 0.f;

  gload_lds16((const char*)kbh + (size_t)srow * 128 + scb,
              (char*)&Ks[0][0] + srow * 128);
  gload_lds16((const char*)vbh + (size_t)srow * 2048 + scb,
              (char*)&Vs[0][0] + srow * 128);
  __syncthreads();

  int buf = 0;
  for (int jt = 0; jt <= qbA; ++jt) {
    if (jt < qbA) {
      int nt = jt + 1;
      gload_lds16((const char*)kbh + (size_t)(nt * 64 + srow) * 128 + scb,
                  (char*)&Ks[buf ^ 1][0] + srow * 128);
      gload_lds16((const char*)vbh + (size_t)srow * 2048 + nt * 128 + scb,
                  (char*)&Vs[buf ^ 1][0] + srow * 128);
    }
    if (jt <= qtile) {   // wave-uniform
      // QK^T swapped, C initialized with mask bias (free masking):
      // sacc[n][jj] = S[k = n*16+lg*4+jj][q = l15]
      f32x4 sacc[4];
#pragma unroll
      for (int n = 0; n < 4; ++n)
        sacc[n] = *(const f32x4*)(maskAdd + (size_t)b * TT + jt * 64 + n * 16 + lg * 4);
      __builtin_amdgcn_s_setprio(1);
#pragma unroll
      for (int c = 0; c < 2; ++c) {
        f16x8 qc = (c == 0) ? qf0 : qf1;
#pragma unroll
        for (int n = 0; n < 4; ++n) {
          int krow = n * 16 + l15;
          const f16x8 kf = *(const f16x8*)((const char*)&Ks[buf][0] + krow * 128 + ((c * 64 + lg * 16) ^ lsw));
          sacc[n] = mfma16h(kf, qc, sacc[n]);
        }
      }
      __builtin_amdgcn_s_setprio(0);
      if (jt == qtile) {
        const int qloc8 = (wloc * 16 + l15) >> 3;
#pragma unroll
        for (int n = 0; n < 4; ++n)
#pragma unroll
          for (int jj = 0; jj < 4; ++jj) {
            int kloc = n * 16 + lg * 4 + jj;
            if ((kloc >> 3) > qloc8) sacc[n][jj] = -1e30f;
          }
      }
      // per-lane max (max3-fusable tree over 16)
      float t0 = fmaxf(fmaxf(sacc[0][0], sacc[0][1]), fmaxf(sacc[0][2], sacc[0][3]));
      float t1 = fmaxf(fmaxf(sacc[1][0], sacc[1][1]), fmaxf(sacc[1][2], sacc[1][3]));
      float t2 = fmaxf(fmaxf(sacc[2][0], sacc[2][1]), fmaxf(sacc[2][2], sacc[2][3]));
      float t3 = fmaxf(fmaxf(sacc[3][0], sacc[3][1]), fmaxf(sacc[3][2], sacc[3][3]));
      float pmL = fmaxf(fmaxf(t0, t1), fmaxf(t2, t3));
      // defer-max: only do the full rescale when bound exceeded
      if (!__all(pmL <= mrun + 8.0f)) {
        float pm = fmaxf(pmL, __shfl_xor(pmL, 16));
        pm = fmaxf(pm, __shfl_xor(pm, 32));
        float mnew = fmaxf(mrun, pm);
        float alpha = __expf(mrun - mnew);
        mrun = mnew;
        lrun *= alpha;
        float ab[4];
#pragma unroll
        for (int jj = 0; jj < 4; ++jj) ab[jj] = __shfl(alpha, lg * 4 + jj);
#pragma unroll
        for (int dt = 0; dt < 4; ++dt)
#pragma unroll
          for (int jj = 0; jj < 4; ++jj) yacc[dt][jj] *= ab[jj];
      }
      // P = exp(S - mrun) (bounded by e^8), packed fp16 -> LDS
      float psum = 0.f;
#pragma unroll
      for (int n = 0; n < 4; ++n) {
        float p0 = __expf(sacc[n][0] - mrun);
        float p1 = __expf(sacc[n][1] - mrun);
        float p2 = __expf(sacc[n][2] - mrun);
        float p3 = __expf(sacc[n][3] - mrun);
        psum += (p0 + p1) + (p2 + p3);
        uint2 pw;
        pw.x = __builtin_bit_cast(unsigned, __builtin_amdgcn_cvt_pkrtz(p0, p1));
        pw.y = __builtin_bit_cast(unsigned, __builtin_amdgcn_cvt_pkrtz(p2, p3));
        *(uint2*)((char*)&Pl[w][0] + l15 * 128 + ((n * 32 + lg * 8) ^ lsw)) = pw;
      }
      psum += __shfl_xor(psum, 16);
      psum += __shfl_xor(psum, 32);
      lrun += psum;
      // PV
      __builtin_amdgcn_s_setprio(1);
#pragma unroll
      for (int c = 0; c < 2; ++c) {
        const f16x8 pa = *(const f16x8*)((const char*)&Pl[w][0] + l15 * 128 + ((c * 64 + lg * 16) ^ lsw));
#pragma unroll
        for (int dt = 0; dt < 4; ++dt) {
          int vrow = dt * 16 + l15;
          const f16x8 vf = *(const f16x8*)((const char*)&Vs[buf][0] + vrow * 128 + ((c * 64 + lg * 16) ^ lsw));
          yacc[dt] = mfma16h(pa, vf, yacc[dt]);
        }
      }
      __builtin_amdgcn_s_setprio(0);
    }
    __syncthreads();
    buf ^= 1;
  }

  float lb[4];
#pragma unroll
  for (int jj = 0; jj < 4; ++jj) lb[jj] = 1.f / __shfl(lrun, lg * 4 + jj);
#pragma unroll
  for (int dt = 0; dt < 4; ++dt) {
    int col = h * DD + dt * 16 + l15;
#pragma unroll
    for (int jj = 0; jj < 4; ++jj) {
      int row = b * TT + qtile * 64 + wloc * 16 + lg * 4 + jj;
      float y = yacc[dt][jj] * lb[jj];
      Yh[(size_t)row * CC + col] = f2hs(y);
    }
  }
}

// ---------------------------------------------------------------------------
extern "C" void kernel_launch(void* const* d_in, const int* in_sizes, int n_in,
                              void* d_out, int out_size, void* d_ws, size_t ws_size,
                              hipStream_t stream) {
  const float* x    = (const float*)d_in[0];
  const float* mask = (const float*)d_in[1];
  const float* Wq   = (const float*)d_in[2];
  const float* bq   = (const float*)d_in[3];
  const float* Wk   = (const float*)d_in[4];
  const float* bk   = (const float*)d_in[5];
  const float* Wv   = (const float*)d_in[6];
  const float* bv   = (const float*)d_in[7];
  const float* Wp   = (const float*)d_in[8];
  const float* bp   = (const float*)d_in[9];
  float* out = (float*)d_out;

  char* ws = (char*)d_ws;
  short* Xh   = (short*)(ws);                          // 8 MB
  short* Wqkv = (short*)(ws + (size_t)8 * 1048576);    // 1.5 MB
  short* Wpc  = (short*)(ws + (size_t)10 * 1048576);   // 0.5 MB
  short* qo   = (short*)(ws + (size_t)11 * 1048576);   // 8 MB
  short* ko   = (short*)(ws + (size_t)19 * 1048576);   // 8 MB
  short* vt   = (short*)(ws + (size_t)27 * 1048576);   // 8 MB
  short* Yh   = (short*)(ws + (size_t)35 * 1048576);   // 8 MB
  float* maskAdd = (float*)(ws + (size_t)43 * 1048576); // 32 KB

  prep_kernel<<<2048, 256, 0, stream>>>(x, mask, Wq, Wk, Wv, Wp, Xh, Wqkv, Wpc, maskAdd);

  // QKV: M=8192/128=64, N=1536/192=8 -> 512 blocks = 2/CU
  gemm_kernel<192, 0><<<dim3(64, 8), 512, 0, stream>>>(
      Xh, Wqkv, bq, bk, bv, qo, ko, vt, nullptr);

  // attn: 64 bh x 8 pairs = 512 blocks, balanced 17 units each
  attn_kernel<<<dim3(512), 512, 0, stream>>>(qo, ko, vt, maskAdd, Yh);

  // proj: M=8192/128=64, N=512/128=4 -> 256 blocks
  gemm_kernel<128, 1><<<dim3(64, 4), 512, 0, stream>>>(
      Yh, Wpc, bp, nullptr, nullptr, nullptr, nullptr, nullptr, out);
}